// Round 1
// baseline (3784.265 us; speedup 1.0000x reference)
//
#include <hip/hip_runtime.h>

#define NODES   131072
#define EDGES   2097152
#define H       128
#define NB      32        // graphs
#define PP      4096      // nodes per graph

// ============================================================================
// CSR build: histogram -> hierarchical exclusive scan -> fill (bucket by dst)
// ============================================================================
__global__ __launch_bounds__(256) void gnn_hist(const int* __restrict__ dst, int* __restrict__ counts) {
  int e = blockIdx.x * 256 + threadIdx.x;
  if (e < EDGES) atomicAdd(&counts[dst[e]], 1);
}

__global__ __launch_bounds__(256) void gnn_scan1(const int* __restrict__ counts,
                                                 int* __restrict__ rowptr, int* __restrict__ bsum) {
  __shared__ int s[256];
  int t = threadIdx.x;
  int i = blockIdx.x * 256 + t;
  int v = counts[i];
  s[t] = v; __syncthreads();
  for (int off = 1; off < 256; off <<= 1) {
    int u = (t >= off) ? s[t - off] : 0;
    __syncthreads();
    s[t] += u;
    __syncthreads();
  }
  rowptr[i] = s[t] - v;            // block-local exclusive
  if (t == 255) bsum[blockIdx.x] = s[255];
}

__global__ __launch_bounds__(512) void gnn_scan2(const int* __restrict__ bsum, int* __restrict__ boff) {
  __shared__ int s[512];
  int t = threadIdx.x;
  int v = bsum[t];
  s[t] = v; __syncthreads();
  for (int off = 1; off < 512; off <<= 1) {
    int u = (t >= off) ? s[t - off] : 0;
    __syncthreads();
    s[t] += u;
    __syncthreads();
  }
  boff[t] = s[t] - v;              // exclusive block offsets
}

__global__ __launch_bounds__(256) void gnn_scan3(int* __restrict__ rowptr, const int* __restrict__ boff) {
  int i = blockIdx.x * 256 + threadIdx.x;
  rowptr[i] += boff[blockIdx.x];
  if (i == 0) rowptr[NODES] = EDGES;
}

__global__ __launch_bounds__(256) void gnn_fill(const int* __restrict__ src, const int* __restrict__ dst,
                                                const float* __restrict__ ew, int* __restrict__ cursor,
                                                int* __restrict__ es, float* __restrict__ ewt) {
  int e = blockIdx.x * 256 + threadIdx.x;
  if (e < EDGES) {
    int d = dst[e];
    int p = atomicAdd(&cursor[d], 1);
    es[p]  = src[e];
    ewt[p] = ew[e];
  }
}

// ============================================================================
// t[i,:] = sum_{e in CSR[i]} ew_e * x[src_e,:]   (one wave per node)
// ============================================================================
__global__ __launch_bounds__(256) void gnn_agg(const float* __restrict__ X, const int* __restrict__ rowptr,
                                               const int* __restrict__ es, const float* __restrict__ ewt,
                                               float* __restrict__ T) {
  int wave = threadIdx.x >> 6, lane = threadIdx.x & 63;
  long node = (long)blockIdx.x * 4 + wave;
  int e0 = rowptr[node], e1 = rowptr[node + 1];
  float a0 = 0.f, a1 = 0.f;
  for (int e = e0; e < e1; ++e) {
    int s = es[e];
    float w = ewt[e];
    a0 = fmaf(w, X[(long)s * H + lane], a0);
    a1 = fmaf(w, X[(long)s * H + 64 + lane], a1);
  }
  T[node * H + lane] = a0;
  T[node * H + 64 + lane] = a1;
}

// ============================================================================
// weight prep: Wc = W[l] @ wi.T  (128x384), whT = wh.T (128x384)
// ============================================================================
__global__ __launch_bounds__(384) void gnn_prep_wc(const float* __restrict__ Wl, const float* __restrict__ wi,
                                                   float* __restrict__ Wc) {
  __shared__ float wrow[128];
  int k = blockIdx.x, j = threadIdx.x;
  if (j < 128) wrow[j] = Wl[k * 128 + j];
  __syncthreads();
  float acc = 0.f;
  for (int m = 0; m < 128; ++m) acc = fmaf(wrow[m], wi[j * 128 + m], acc);
  Wc[k * 384 + j] = acc;
}

__global__ __launch_bounds__(384) void gnn_prep_whT(const float* __restrict__ wh1, const float* __restrict__ wh2,
                                                    float* __restrict__ whT) {
  int c = blockIdx.x >> 7, k = blockIdx.x & 127, j = threadIdx.x;
  const float* wh = c ? wh2 : wh1;
  whT[((long)c * 128 + k) * 384 + j] = wh[j * 128 + k];
}

// ============================================================================
// generic GEMM: C[rows x OUT] = act(A[rows x K] @ W[K x OUT] + bias)
// 64x64 tile, 256 threads, 4x4 microtile. BMODE 0: bias[j]; 1: bias[(row>>12)*OUT+j]
// ============================================================================
#define GFMA(i, av) \
  acc[(i)*4+0] = fmaf((av), wv.x, acc[(i)*4+0]); \
  acc[(i)*4+1] = fmaf((av), wv.y, acc[(i)*4+1]); \
  acc[(i)*4+2] = fmaf((av), wv.z, acc[(i)*4+2]); \
  acc[(i)*4+3] = fmaf((av), wv.w, acc[(i)*4+3]);

template<int ACT, int BMODE>
__global__ __launch_bounds__(256) void gnn_gemm(const float* __restrict__ A, const float* __restrict__ W,
                                                const float* __restrict__ bias, float* __restrict__ C,
                                                int K, int OUT) {
  __shared__ float AsT[16][68];   // [k][row]
  __shared__ float Ws[16][68];    // [k][col]
  const int tid = threadIdx.x;
  const int tx = tid & 15, ty = tid >> 4;
  const long row0 = (long)blockIdx.y * 64;
  const int col0 = blockIdx.x * 64;
  const int lr  = tid >> 2;           // 0..63
  const int lk4 = (tid & 3) * 4;      // 0,4,8,12
  const int wk  = tid >> 4;           // 0..15
  const int wj4 = (tid & 15) * 4;     // 0..60
  float acc[16];
#pragma unroll
  for (int i = 0; i < 16; ++i) acc[i] = 0.f;

  for (int kc = 0; kc < K; kc += 16) {
    float4 a = *(const float4*)(A + (row0 + lr) * K + kc + lk4);
    float4 w = *(const float4*)(W + (long)(kc + wk) * OUT + col0 + wj4);
    AsT[lk4 + 0][lr] = a.x; AsT[lk4 + 1][lr] = a.y; AsT[lk4 + 2][lr] = a.z; AsT[lk4 + 3][lr] = a.w;
    *(float4*)(&Ws[wk][wj4]) = w;
    __syncthreads();
#pragma unroll
    for (int k = 0; k < 16; ++k) {
      float4 av = *(const float4*)(&AsT[k][ty * 4]);
      float4 wv = *(const float4*)(&Ws[k][tx * 4]);
      GFMA(0, av.x) GFMA(1, av.y) GFMA(2, av.z) GFMA(3, av.w)
    }
    __syncthreads();
  }
#pragma unroll
  for (int i = 0; i < 4; ++i) {
    long row = row0 + ty * 4 + i;
    const float* bp = (BMODE == 0) ? bias : (bias + (row >> 12) * OUT);
    int j = col0 + tx * 4;
    float4 o;
    o.x = acc[i * 4 + 0] + bp[j + 0];
    o.y = acc[i * 4 + 1] + bp[j + 1];
    o.z = acc[i * 4 + 2] + bp[j + 2];
    o.w = acc[i * 4 + 3] + bp[j + 3];
    if (ACT) { o.x = fmaxf(o.x, 0.f); o.y = fmaxf(o.y, 0.f); o.z = fmaxf(o.z, 0.f); o.w = fmaxf(o.w, 0.f); }
    *(float4*)(C + row * OUT + j) = o;
  }
}
#undef GFMA

// ============================================================================
// fused GRU: Y = GRUCell(m = T@W (folded into Wc), h = X); optional output relu
// block: 64 rows, 256 threads, each thread 8 rows x 4 cols
// ============================================================================
__device__ __forceinline__ float gnn_sigmoid(float x) { return 1.f / (1.f + __expf(-x)); }

#define RFMA(i, av) \
  acc[(i)*4+0] = fmaf((av), w.x, acc[(i)*4+0]); \
  acc[(i)*4+1] = fmaf((av), w.y, acc[(i)*4+1]); \
  acc[(i)*4+2] = fmaf((av), w.z, acc[(i)*4+2]); \
  acc[(i)*4+3] = fmaf((av), w.w, acc[(i)*4+3]);

__device__ __forceinline__ void gnn_mm(const float* __restrict__ Wg, const float (*At)[64],
                                       int tx, int ty, float* __restrict__ acc) {
  for (int k = 0; k < 128; ++k) {
    float4 w  = *(const float4*)(Wg + (long)k * 384 + tx * 4);
    float4 a0 = *(const float4*)(&At[k][ty * 8]);
    float4 a1 = *(const float4*)(&At[k][ty * 8 + 4]);
    RFMA(0, a0.x) RFMA(1, a0.y) RFMA(2, a0.z) RFMA(3, a0.w)
    RFMA(4, a1.x) RFMA(5, a1.y) RFMA(6, a1.z) RFMA(7, a1.w)
  }
}
#undef RFMA

template<int RELU>
__global__ __launch_bounds__(256) void gnn_gru(const float* __restrict__ T, const float* __restrict__ X,
                                               const float* __restrict__ Wc, const float* __restrict__ WhT,
                                               const float* __restrict__ bi, const float* __restrict__ bh,
                                               float* __restrict__ Y) {
  __shared__ float Tt[128][64];
  __shared__ float Xt[128][64];
  const int tid = threadIdx.x;
  const int tx = tid & 31, ty = tid >> 5;
  const long row0 = (long)blockIdx.x * 64;
  {
    const int lr = tid >> 2;
    const int lk4 = (tid & 3) * 4;
#pragma unroll
    for (int kc = 0; kc < 128; kc += 16) {
      int k = kc + lk4;
      float4 a = *(const float4*)(T + (row0 + lr) * H + k);
      Tt[k + 0][lr] = a.x; Tt[k + 1][lr] = a.y; Tt[k + 2][lr] = a.z; Tt[k + 3][lr] = a.w;
      float4 b = *(const float4*)(X + (row0 + lr) * H + k);
      Xt[k + 0][lr] = b.x; Xt[k + 1][lr] = b.y; Xt[k + 2][lr] = b.z; Xt[k + 3][lr] = b.w;
    }
  }
  __syncthreads();

  float rg[32], nn[32];
  {   // r gate
    float acc[32];
#pragma unroll
    for (int i = 0; i < 32; ++i) acc[i] = 0.f;
    gnn_mm(Wc + 0, Tt, tx, ty, acc);
    gnn_mm(WhT + 0, Xt, tx, ty, acc);
#pragma unroll
    for (int rr = 0; rr < 8; ++rr)
#pragma unroll
      for (int c = 0; c < 4; ++c) {
        int col = tx * 4 + c, idx = rr * 4 + c;
        rg[idx] = gnn_sigmoid(acc[idx] + bi[col] + bh[col]);
      }
  }
  {   // n gate: n = tanh(inn + bi_n + r*(hn + bh_n))
    float ah[32], ai[32];
#pragma unroll
    for (int i = 0; i < 32; ++i) { ah[i] = 0.f; ai[i] = 0.f; }
    gnn_mm(WhT + 256, Xt, tx, ty, ah);
    gnn_mm(Wc + 256, Tt, tx, ty, ai);
#pragma unroll
    for (int rr = 0; rr < 8; ++rr)
#pragma unroll
      for (int c = 0; c < 4; ++c) {
        int col = tx * 4 + c, idx = rr * 4 + c;
        nn[idx] = tanhf(ai[idx] + bi[256 + col] + rg[idx] * (ah[idx] + bh[256 + col]));
      }
  }
  {   // z gate + combine + store
    float acc[32];
#pragma unroll
    for (int i = 0; i < 32; ++i) acc[i] = 0.f;
    gnn_mm(Wc + 128, Tt, tx, ty, acc);
    gnn_mm(WhT + 128, Xt, tx, ty, acc);
#pragma unroll
    for (int rr = 0; rr < 8; ++rr) {
      int row = ty * 8 + rr;
      float4 o;
#pragma unroll
      for (int c = 0; c < 4; ++c) {
        int col = tx * 4 + c, idx = rr * 4 + c;
        float z = gnn_sigmoid(acc[idx] + bi[128 + col] + bh[128 + col]);
        float h = Xt[col][row];
        float v = (1.f - z) * nn[idx] + z * h;
        if (RELU) v = fmaxf(v, 0.f);
        ((float*)&o)[c] = v;
      }
      *(float4*)(Y + (row0 + row) * H + tx * 4) = o;
    }
  }
}

// ============================================================================
// head: pool, per-graph bias, item-value init, final bound reduction
// ============================================================================
__global__ __launch_bounds__(128) void gnn_pool(const float* __restrict__ X3, float* __restrict__ ge) {
  int b = blockIdx.x >> 3, chunk = blockIdx.x & 7, t = threadIdx.x;
  long base = ((long)b * PP + chunk * 512) * H;
  float acc = 0.f;
  for (int p = 0; p < 512; ++p) acc += X3[base + (long)p * H + t];
  atomicAdd(&ge[b * H + t], acc);
}

__global__ __launch_bounds__(256) void gnn_gbias(const float* __restrict__ ge, const float* __restrict__ Wl1b,
                                                 const float* __restrict__ bl1, float* __restrict__ gb) {
  __shared__ float g[128];
  int b = blockIdx.x, t = threadIdx.x;
  if (t < 128) g[t] = ge[b * H + t] * (1.f / 4096.f);
  __syncthreads();
  float acc = bl1[t];
  for (int k = 0; k < 128; ++k) acc = fmaf(g[k], Wl1b[k * 256 + t], acc);
  gb[b * 256 + t] = acc;
}

__global__ __launch_bounds__(256) void gnn_item(const float* __restrict__ iv, const int* __restrict__ vvs,
                                                float* __restrict__ out) {
  __shared__ float s[256];
  int b = blockIdx.x, t = threadIdx.x;
  float v = iv[b * 256 + t] * (float)vvs[(long)b * PP + t];   // sol[b,0,n]
  s[t] = v; __syncthreads();
  for (int off = 128; off > 0; off >>= 1) {
    if (t < off) s[t] += s[t + off];
    __syncthreads();
  }
  if (t == 0) out[b] = s[0];
}

__global__ __launch_bounds__(256) void gnn_bound(const float* __restrict__ U2, const float* __restrict__ wl3,
                                                 const float* __restrict__ bl3, const int* __restrict__ vvs,
                                                 float* __restrict__ out) {
  int tid = threadIdx.x;
  int wave = tid >> 6, lane = tid & 63;
  int b = blockIdx.x >> 6;
  long node0 = (long)blockIdx.x * 64 + wave * 16;
  float w0 = wl3[lane], w1 = wl3[64 + lane];
  float bl = bl3[0];
  float acc = 0.f;
  for (int i = 0; i < 16; ++i) {
    long node = node0 + i;
    float p = U2[node * H + lane] * w0 + U2[node * H + 64 + lane] * w1;
#pragma unroll
    for (int off = 32; off > 0; off >>= 1) p += __shfl_down(p, off);
    if (lane == 0) {
      int pp = (int)(node & (PP - 1));
      int m = pp >> 8, n = pp & 255;
      if (m != 0) {
        float dx = (float)(vvs[((long)b << 12) + n] - vvs[((long)b << 12) + pp]);
        acc += (p + bl) * dx;
      }
    }
  }
  __shared__ float s[4];
  if (lane == 0) s[wave] = acc;
  __syncthreads();
  if (tid == 0) atomicAdd(&out[b], s[0] + s[1] + s[2] + s[3]);
}

// ============================================================================
extern "C" void kernel_launch(void* const* d_in, const int* in_sizes, int n_in,
                              void* d_out, int out_size, void* d_ws, size_t ws_size,
                              hipStream_t stream) {
  const float* G      = (const float*)d_in[0];
  const int*   ei     = (const int*)d_in[1];
  const int*   esrc   = ei;
  const int*   edst   = ei + EDGES;
  const float* ew     = (const float*)d_in[2];
  const int*   vvs    = (const int*)d_in[4];
  const float* iv     = (const float*)d_in[5];
  const float* W_emb1 = (const float*)d_in[6];
  const float* b_emb1 = (const float*)d_in[7];
  const float* W_emb2 = (const float*)d_in[8];
  const float* b_emb2 = (const float*)d_in[9];
  const float* c1_W   = (const float*)d_in[10];
  const float* c1_wi  = (const float*)d_in[11];
  const float* c1_wh  = (const float*)d_in[12];
  const float* c1_bi  = (const float*)d_in[13];
  const float* c1_bh  = (const float*)d_in[14];
  const float* c2_W   = (const float*)d_in[15];
  const float* c2_wi  = (const float*)d_in[16];
  const float* c2_wh  = (const float*)d_in[17];
  const float* c2_bi  = (const float*)d_in[18];
  const float* c2_bh  = (const float*)d_in[19];
  const float* W_g1   = (const float*)d_in[20];
  const float* b_g1   = (const float*)d_in[21];
  const float* W_g2   = (const float*)d_in[22];
  const float* b_g2   = (const float*)d_in[23];
  const float* W_l1   = (const float*)d_in[24];
  const float* b_l1   = (const float*)d_in[25];
  const float* W_l2   = (const float*)d_in[26];
  const float* b_l2   = (const float*)d_in[27];
  const float* W_l3   = (const float*)d_in[28];
  const float* b_l3   = (const float*)d_in[29];
  float* out = (float*)d_out;
  (void)in_sizes; (void)n_in; (void)out_size; (void)ws_size;

  // ---- workspace carve (needs ~211 MiB) ----
  char* wsb = (char*)d_ws;
  size_t off = 0;
  auto carve = [&](size_t bytes) -> char* {
    char* p = wsb + off;
    off += (bytes + 255) & ~(size_t)255;
    return p;
  };
  float* b0     = (float*)carve(sizeof(float) * (size_t)NODES * H);   // b0,b1 contiguous: u1 overlays both
  float* b1     = (float*)carve(sizeof(float) * (size_t)NODES * H);
  float* b2     = (float*)carve(sizeof(float) * (size_t)NODES * H);
  float* Wc     = (float*)carve(sizeof(float) * 4 * H * 384);
  float* whT    = (float*)carve(sizeof(float) * 2 * H * 384);
  int*   rowptr = (int*)carve(sizeof(int) * (NODES + 1));
  int*   cnt    = (int*)carve(sizeof(int) * NODES);      // counts, later cursor
  int*   bsum   = (int*)carve(sizeof(int) * 512);
  int*   boff   = (int*)carve(sizeof(int) * 512);
  int*   es     = (int*)carve(sizeof(int) * EDGES);
  float* ewt    = (float*)carve(sizeof(float) * EDGES);
  float* ge     = (float*)carve(sizeof(float) * NB * H);
  float* gb     = (float*)carve(sizeof(float) * NB * 256);

  // ---- CSR build ----
  hipMemsetAsync(cnt, 0, sizeof(int) * NODES, stream);
  hipMemsetAsync(ge, 0, sizeof(float) * NB * H, stream);
  gnn_hist<<<EDGES / 256, 256, 0, stream>>>(edst, cnt);
  gnn_scan1<<<512, 256, 0, stream>>>(cnt, rowptr, bsum);
  gnn_scan2<<<1, 512, 0, stream>>>(bsum, boff);
  gnn_scan3<<<512, 256, 0, stream>>>(rowptr, boff);
  hipMemcpyAsync(cnt, rowptr, sizeof(int) * NODES, hipMemcpyDeviceToDevice, stream);  // cursor
  gnn_fill<<<EDGES / 256, 256, 0, stream>>>(esrc, edst, ew, cnt, es, ewt);

  // ---- weight prep: Wc[l] = W[l] @ wi.T ; whT = wh.T ----
  gnn_prep_wc<<<128, 384, 0, stream>>>(c1_W,             c1_wi, Wc + 0 * 128 * 384);
  gnn_prep_wc<<<128, 384, 0, stream>>>(c1_W + 128 * 128, c1_wi, Wc + 1 * 128 * 384);
  gnn_prep_wc<<<128, 384, 0, stream>>>(c2_W,             c2_wi, Wc + 2 * 128 * 384);
  gnn_prep_wc<<<128, 384, 0, stream>>>(c2_W + 128 * 128, c2_wi, Wc + 3 * 128 * 384);
  gnn_prep_whT<<<256, 384, 0, stream>>>(c1_wh, c2_wh, whT);

  // ---- embeddings ----
  gnn_gemm<1, 0><<<dim3(2, NODES / 64), 256, 0, stream>>>(G,  W_emb1, b_emb1, b1, 16, 128);
  gnn_gemm<1, 0><<<dim3(2, NODES / 64), 256, 0, stream>>>(b1, W_emb2, b_emb2, b0, 128, 128);

  // ---- conv1 (x in b0) ----
  gnn_agg<<<NODES / 4, 256, 0, stream>>>(b0, rowptr, es, ewt, b1);
  gnn_gru<0><<<NODES / 64, 256, 0, stream>>>(b1, b0, Wc + 0 * 128 * 384, whT, c1_bi, c1_bh, b2);
  gnn_agg<<<NODES / 4, 256, 0, stream>>>(b2, rowptr, es, ewt, b1);
  gnn_gru<1><<<NODES / 64, 256, 0, stream>>>(b1, b2, Wc + 1 * 128 * 384, whT, c1_bi, c1_bh, b0);

  // ---- conv2 (x in b0) ----
  gnn_agg<<<NODES / 4, 256, 0, stream>>>(b0, rowptr, es, ewt, b1);
  gnn_gru<0><<<NODES / 64, 256, 0, stream>>>(b1, b0, Wc + 2 * 128 * 384, whT + 128 * 384, c2_bi, c2_bh, b2);
  gnn_agg<<<NODES / 4, 256, 0, stream>>>(b2, rowptr, es, ewt, b1);
  gnn_gru<1><<<NODES / 64, 256, 0, stream>>>(b1, b2, Wc + 3 * 128 * 384, whT + 128 * 384, c2_bi, c2_bh, b0);

  // ---- head GEMMs ----
  gnn_gemm<1, 0><<<dim3(2, NODES / 64), 256, 0, stream>>>(b0, W_g1, b_g1, b1, 128, 128);
  gnn_gemm<0, 0><<<dim3(2, NODES / 64), 256, 0, stream>>>(b1, W_g2, b_g2, b2, 128, 128);   // x3 in b2

  // ---- pool + per-graph bias (folds ge @ W_l1[128:] + b_l1) ----
  gnn_pool<<<NB * 8, 128, 0, stream>>>(b2, ge);
  gnn_gbias<<<NB, 256, 0, stream>>>(ge, W_l1 + 128 * 256, b_l1, gb);

  // ---- MLP: l1 (graph-bias), l2, l3+reduction ----
  gnn_gemm<1, 1><<<dim3(4, NODES / 64), 256, 0, stream>>>(b2, W_l1, gb, b0, 128, 256);   // u1 in b0(+b1)
  gnn_gemm<1, 0><<<dim3(2, NODES / 64), 256, 0, stream>>>(b0, W_l2, b_l2, b2, 256, 128); // u2 in b2
  gnn_item<<<NB, 256, 0, stream>>>(iv, vvs, out);
  gnn_bound<<<NODES / 64, 256, 0, stream>>>(b2, W_l3, b_l3, vvs, out);
}

// Round 2
// 1898.176 us; speedup vs baseline: 1.9936x; 1.9936x over previous
//
#include <hip/hip_runtime.h>

#define NODES   131072
#define EDGES   2097152
#define H       128
#define NB      32        // graphs
#define PP      4096      // nodes per graph

typedef short bf16x8 __attribute__((ext_vector_type(8)));
typedef float f32x4  __attribute__((ext_vector_type(4)));

// ============================================================================
// CSR build: histogram -> hierarchical exclusive scan -> fill (bucket by dst)
// ============================================================================
__global__ __launch_bounds__(256) void gnn_hist(const int* __restrict__ dst, int* __restrict__ counts) {
  int e = blockIdx.x * 256 + threadIdx.x;
  if (e < EDGES) atomicAdd(&counts[dst[e]], 1);
}

__global__ __launch_bounds__(256) void gnn_scan1(const int* __restrict__ counts,
                                                 int* __restrict__ rowptr, int* __restrict__ bsum) {
  __shared__ int s[256];
  int t = threadIdx.x;
  int i = blockIdx.x * 256 + t;
  int v = counts[i];
  s[t] = v; __syncthreads();
  for (int off = 1; off < 256; off <<= 1) {
    int u = (t >= off) ? s[t - off] : 0;
    __syncthreads();
    s[t] += u;
    __syncthreads();
  }
  rowptr[i] = s[t] - v;            // block-local exclusive
  if (t == 255) bsum[blockIdx.x] = s[255];
}

__global__ __launch_bounds__(512) void gnn_scan2(const int* __restrict__ bsum, int* __restrict__ boff) {
  __shared__ int s[512];
  int t = threadIdx.x;
  int v = bsum[t];
  s[t] = v; __syncthreads();
  for (int off = 1; off < 512; off <<= 1) {
    int u = (t >= off) ? s[t - off] : 0;
    __syncthreads();
    s[t] += u;
    __syncthreads();
  }
  boff[t] = s[t] - v;              // exclusive block offsets
}

__global__ __launch_bounds__(256) void gnn_scan3(int* __restrict__ rowptr, const int* __restrict__ boff) {
  int i = blockIdx.x * 256 + threadIdx.x;
  rowptr[i] += boff[blockIdx.x];
  if (i == 0) rowptr[NODES] = EDGES;
}

__global__ __launch_bounds__(256) void gnn_fill(const int* __restrict__ src, const int* __restrict__ dst,
                                                const float* __restrict__ ew, int* __restrict__ cursor,
                                                int* __restrict__ es, float* __restrict__ ewt) {
  int e = blockIdx.x * 256 + threadIdx.x;
  if (e < EDGES) {
    int d = dst[e];
    int p = atomicAdd(&cursor[d], 1);
    es[p]  = src[e];
    ewt[p] = ew[e];
  }
}

// ============================================================================
// t[i,:] = sum_{e in CSR[i]} ew_e * x[src_e,:]   (one wave per node)
// ============================================================================
__global__ __launch_bounds__(256) void gnn_agg(const float* __restrict__ X, const int* __restrict__ rowptr,
                                               const int* __restrict__ es, const float* __restrict__ ewt,
                                               float* __restrict__ T) {
  int wave = threadIdx.x >> 6, lane = threadIdx.x & 63;
  long node = (long)blockIdx.x * 4 + wave;
  int e0 = rowptr[node], e1 = rowptr[node + 1];
  float a0 = 0.f, a1 = 0.f;
  for (int e = e0; e < e1; ++e) {
    int s = es[e];
    float w = ewt[e];
    a0 = fmaf(w, X[(long)s * H + lane], a0);
    a1 = fmaf(w, X[(long)s * H + 64 + lane], a1);
  }
  T[node * H + lane] = a0;
  T[node * H + 64 + lane] = a1;
}

// ============================================================================
// weight prep: Wc = W[l] @ wi.T  (128x384), whT = wh.T (128x384)
// ============================================================================
__global__ __launch_bounds__(384) void gnn_prep_wc(const float* __restrict__ Wl, const float* __restrict__ wi,
                                                   float* __restrict__ Wc) {
  __shared__ float wrow[128];
  int k = blockIdx.x, j = threadIdx.x;
  if (j < 128) wrow[j] = Wl[k * 128 + j];
  __syncthreads();
  float acc = 0.f;
  for (int m = 0; m < 128; ++m) acc = fmaf(wrow[m], wi[j * 128 + m], acc);
  Wc[k * 384 + j] = acc;
}

__global__ __launch_bounds__(384) void gnn_prep_whT(const float* __restrict__ wh1, const float* __restrict__ wh2,
                                                    float* __restrict__ whT) {
  int c = blockIdx.x >> 7, k = blockIdx.x & 127, j = threadIdx.x;
  const float* wh = c ? wh2 : wh1;
  whT[((long)c * 128 + k) * 384 + j] = wh[j * 128 + k];
}

// ============================================================================
// bf16 helpers + MFMA fragment plumbing
// A-frag layout (16x16x32): A[m=lane&15][k=(lane>>4)*8+j]
// B-frag layout:            B[k=(lane>>4)*8+j][n=lane&15]
// C/D layout:               col=lane&15, row=(lane>>4)*4+reg
// LDS A staging: slot(ktq,row) = ktq*64 + (row ^ (ktq&7)), 16B per slot
// ============================================================================
__device__ __forceinline__ unsigned gnn_pack2bf(float a, float b) {
  union { float f; unsigned u; } x, y; x.f = a; y.f = b;
  unsigned ua = (x.u + 0x7FFFu + ((x.u >> 16) & 1u)) >> 16;
  unsigned ub = (y.u + 0x7FFFu + ((y.u >> 16) & 1u)) >> 16;
  return ua | (ub << 16);
}

__device__ __forceinline__ unsigned short gnn_f2bf(float a) {
  union { float f; unsigned u; } x; x.f = a;
  return (unsigned short)((x.u + 0x7FFFu + ((x.u >> 16) & 1u)) >> 16);
}

template<int K>
__device__ __forceinline__ void gnn_stage(const float* __restrict__ A, long row0,
                                          unsigned short* lds, int tid) {
  constexpr int KQ = K / 4;     // float4s per row
#pragma unroll
  for (int it = 0; it < KQ / 4; ++it) {
    int idx = it * 256 + tid;
    int row = idx / KQ, kq = idx % KQ;
    float4 a = *(const float4*)(A + (row0 + row) * K + kq * 4);
    int ktq = kq >> 1;
    int slot = ktq * 64 + (row ^ (ktq & 7));
    unsigned* p = (unsigned*)(lds + slot * 8 + (kq & 1) * 4);
    p[0] = gnn_pack2bf(a.x, a.y);
    p[1] = gnn_pack2bf(a.z, a.w);
  }
}

__device__ __forceinline__ bf16x8 gnn_afrag(const unsigned short* lds, int rt, int ktq, int l16) {
  int slot = ktq * 64 + ((rt * 16 + l16) ^ (ktq & 7));
  return *(const bf16x8*)(lds + slot * 8);
}

__device__ __forceinline__ bf16x8 gnn_bfrag(const unsigned short* __restrict__ pk,
                                            int ct, int kt, int KT, int lane) {
  return *(const bf16x8*)(pk + (((long)(ct * KT + kt)) * 64 + lane) * 8);
}

__device__ __forceinline__ float gnn_sig(float x)  { return 1.f / (1.f + __expf(-x)); }
__device__ __forceinline__ float gnn_tanh(float x) { return 1.f - 2.f / (1.f + __expf(2.f * x)); }

// pack fp32 weight into B-fragment bf16 layout: dst frag (ct,kt) at [(ct*KT+kt)*64+lane]*8 halves
// source element: k<ksplit ? W0[k*LD + coff + col] : W1[(k-ksplit)*LD + coff + col]
__global__ __launch_bounds__(64) void gnn_pack(const float* __restrict__ W0, const float* __restrict__ W1,
                                               int ksplit, int LD, int coff, int KT,
                                               unsigned short* __restrict__ dst) {
  int b = blockIdx.x;
  int kt = b % KT, ct = b / KT;
  int lane = threadIdx.x;
  int col = ct * 16 + (lane & 15) + coff;
  int kb = kt * 32 + ((lane >> 4) & 3) * 8;
  unsigned short h[8];
#pragma unroll
  for (int j = 0; j < 8; ++j) {
    int k = kb + j;
    float v = (k < ksplit) ? W0[(long)k * LD + col] : W1[(long)(k - ksplit) * LD + col];
    h[j] = gnn_f2bf(v);
  }
  uint4 o;
  o.x = (unsigned)h[0] | ((unsigned)h[1] << 16);
  o.y = (unsigned)h[2] | ((unsigned)h[3] << 16);
  o.z = (unsigned)h[4] | ((unsigned)h[5] << 16);
  o.w = (unsigned)h[6] | ((unsigned)h[7] << 16);
  ((uint4*)dst)[(long)b * 64 + lane] = o;
}

// ============================================================================
// MFMA GEMM: C[M x N] = act(A[M x K] @ Wpk + bias), 64-row blocks, 256 thr.
// wave w covers cols [w*N/4, (w+1)*N/4). BMODE 0: bias[j]; 1: bias[(row>>12)*N+j]
// ============================================================================
template<int K, int N, int ACT, int BMODE>
__global__ __launch_bounds__(256) void gnn_mgemm(const float* __restrict__ A,
                                                 const unsigned short* __restrict__ pk,
                                                 const float* __restrict__ bias,
                                                 float* __restrict__ C) {
  constexpr int KT = K / 32;
  constexpr int CT = N / 64;       // col-tiles per wave
  __shared__ unsigned short As[64 * K];
  const int tid = threadIdx.x;
  const int lane = tid & 63, wave = tid >> 6;
  const int quad = lane >> 4, l16 = lane & 15;
  const long row0 = (long)blockIdx.x * 64;
  gnn_stage<K>(A, row0, As, tid);
  __syncthreads();

  f32x4 zero4 = {0.f, 0.f, 0.f, 0.f};
  f32x4 acc[4][CT];
#pragma unroll
  for (int rt = 0; rt < 4; ++rt)
#pragma unroll
    for (int ct = 0; ct < CT; ++ct) acc[rt][ct] = zero4;

#pragma unroll
  for (int kt = 0; kt < KT; ++kt) {
    int ktq = kt * 4 + quad;
    bf16x8 af[4];
#pragma unroll
    for (int rt = 0; rt < 4; ++rt) af[rt] = gnn_afrag(As, rt, ktq, l16);
#pragma unroll
    for (int ct = 0; ct < CT; ++ct) {
      bf16x8 bf = gnn_bfrag(pk, wave * CT + ct, kt, KT, lane);
#pragma unroll
      for (int rt = 0; rt < 4; ++rt)
        acc[rt][ct] = __builtin_amdgcn_mfma_f32_16x16x32_bf16(af[rt], bf, acc[rt][ct], 0, 0, 0);
    }
  }

  const float* bp = (BMODE == 0) ? bias : (bias + (row0 >> 12) * N);
#pragma unroll
  for (int ct = 0; ct < CT; ++ct) {
    int col = (wave * CT + ct) * 16 + l16;
    float bv = bp[col];
#pragma unroll
    for (int rt = 0; rt < 4; ++rt) {
      long row = row0 + rt * 16 + quad * 4;
#pragma unroll
      for (int r = 0; r < 4; ++r) {
        float v = acc[rt][ct][r] + bv;
        if (ACT) v = fmaxf(v, 0.f);
        C[(row + r) * N + col] = v;
      }
    }
  }
}

// ============================================================================
// MFMA GRU: Y = GRUCell(m = T@Wc, h = X). 64-row blocks, 256 threads.
// wave w covers gate cols [w*32, w*32+32). r/z fused K=256 over [T|X].
// pkRZ: [256k x 256col] (r cols 0..127, z 128..255); pkAI/pkAH: [128 x 128]
// ============================================================================
template<int RELU>
__global__ __launch_bounds__(256) void gnn_mgru(const float* __restrict__ T, const float* __restrict__ X,
                                                const unsigned short* __restrict__ pkRZ,
                                                const unsigned short* __restrict__ pkAI,
                                                const unsigned short* __restrict__ pkAH,
                                                const float* __restrict__ bi, const float* __restrict__ bh,
                                                float* __restrict__ Y) {
  __shared__ unsigned short Ts[64 * 128];
  __shared__ unsigned short Xs[64 * 128];
  const int tid = threadIdx.x;
  const int lane = tid & 63, wave = tid >> 6;
  const int quad = lane >> 4, l16 = lane & 15;
  const long row0 = (long)blockIdx.x * 64;
  gnn_stage<128>(T, row0, Ts, tid);
  gnn_stage<128>(X, row0, Xs, tid);
  __syncthreads();

  f32x4 zero4 = {0.f, 0.f, 0.f, 0.f};
  f32x4 ai[4][2], ah[4][2], rr[4][2];
#pragma unroll
  for (int rt = 0; rt < 4; ++rt)
#pragma unroll
    for (int c = 0; c < 2; ++c) { ai[rt][c] = zero4; ah[rt][c] = zero4; rr[rt][c] = zero4; }

  // fused K-loop: ai (T), ah (X), r (T,X)
#pragma unroll
  for (int kt = 0; kt < 4; ++kt) {
    int ktq = kt * 4 + quad;
    bf16x8 tf[4], xf[4];
#pragma unroll
    for (int rt = 0; rt < 4; ++rt) { tf[rt] = gnn_afrag(Ts, rt, ktq, l16); xf[rt] = gnn_afrag(Xs, rt, ktq, l16); }
#pragma unroll
    for (int c = 0; c < 2; ++c) {
      int ct = wave * 2 + c;
      bf16x8 bAI = gnn_bfrag(pkAI, ct, kt, 4, lane);
      bf16x8 bAH = gnn_bfrag(pkAH, ct, kt, 4, lane);
      bf16x8 bRT = gnn_bfrag(pkRZ, ct, kt,     8, lane);
      bf16x8 bRX = gnn_bfrag(pkRZ, ct, kt + 4, 8, lane);
#pragma unroll
      for (int rt = 0; rt < 4; ++rt) {
        ai[rt][c] = __builtin_amdgcn_mfma_f32_16x16x32_bf16(tf[rt], bAI, ai[rt][c], 0, 0, 0);
        ah[rt][c] = __builtin_amdgcn_mfma_f32_16x16x32_bf16(xf[rt], bAH, ah[rt][c], 0, 0, 0);
        rr[rt][c] = __builtin_amdgcn_mfma_f32_16x16x32_bf16(tf[rt], bRT, rr[rt][c], 0, 0, 0);
        rr[rt][c] = __builtin_amdgcn_mfma_f32_16x16x32_bf16(xf[rt], bRX, rr[rt][c], 0, 0, 0);
      }
    }
  }

  // biases for this lane's two gate columns
  float brz[2], bzz[2], bin_[2], bhn[2];
#pragma unroll
  for (int c = 0; c < 2; ++c) {
    int col = (wave * 2 + c) * 16 + l16;
    brz[c]  = bi[col] + bh[col];
    bzz[c]  = bi[128 + col] + bh[128 + col];
    bin_[c] = bi[256 + col];
    bhn[c]  = bh[256 + col];
  }

  // n = tanh(ai + bi_n + r*(ah + bh_n))   (n overwrites ai)
#pragma unroll
  for (int rt = 0; rt < 4; ++rt)
#pragma unroll
    for (int c = 0; c < 2; ++c)
#pragma unroll
      for (int r = 0; r < 4; ++r) {
        float rv = gnn_sig(rr[rt][c][r] + brz[c]);
        ai[rt][c][r] = gnn_tanh(ai[rt][c][r] + bin_[c] + rv * (ah[rt][c][r] + bhn[c]));
      }

  // z gate
  f32x4 zz[4][2];
#pragma unroll
  for (int rt = 0; rt < 4; ++rt)
#pragma unroll
    for (int c = 0; c < 2; ++c) zz[rt][c] = zero4;
#pragma unroll
  for (int kt = 0; kt < 4; ++kt) {
    int ktq = kt * 4 + quad;
    bf16x8 tf[4], xf[4];
#pragma unroll
    for (int rt = 0; rt < 4; ++rt) { tf[rt] = gnn_afrag(Ts, rt, ktq, l16); xf[rt] = gnn_afrag(Xs, rt, ktq, l16); }
#pragma unroll
    for (int c = 0; c < 2; ++c) {
      int ct = wave * 2 + c;
      bf16x8 bZT = gnn_bfrag(pkRZ, 8 + ct, kt,     8, lane);
      bf16x8 bZX = gnn_bfrag(pkRZ, 8 + ct, kt + 4, 8, lane);
#pragma unroll
      for (int rt = 0; rt < 4; ++rt) {
        zz[rt][c] = __builtin_amdgcn_mfma_f32_16x16x32_bf16(tf[rt], bZT, zz[rt][c], 0, 0, 0);
        zz[rt][c] = __builtin_amdgcn_mfma_f32_16x16x32_bf16(xf[rt], bZX, zz[rt][c], 0, 0, 0);
      }
    }
  }

  // combine + store (h read fp32 from global X)
#pragma unroll
  for (int rt = 0; rt < 4; ++rt)
#pragma unroll
    for (int c = 0; c < 2; ++c) {
      int col = (wave * 2 + c) * 16 + l16;
      long rowb = row0 + rt * 16 + quad * 4;
#pragma unroll
      for (int r = 0; r < 4; ++r) {
        float z = gnn_sig(zz[rt][c][r] + bzz[c]);
        float h = X[(rowb + r) * H + col];
        float v = (1.f - z) * ai[rt][c][r] + z * h;
        if (RELU) v = fmaxf(v, 0.f);
        Y[(rowb + r) * H + col] = v;
      }
    }
}

// ============================================================================
// fp32 GEMM (kept for emb1, K=16 only)
// ============================================================================
#define GFMA(i, av) \
  acc[(i)*4+0] = fmaf((av), wv.x, acc[(i)*4+0]); \
  acc[(i)*4+1] = fmaf((av), wv.y, acc[(i)*4+1]); \
  acc[(i)*4+2] = fmaf((av), wv.z, acc[(i)*4+2]); \
  acc[(i)*4+3] = fmaf((av), wv.w, acc[(i)*4+3]);

template<int ACT, int BMODE>
__global__ __launch_bounds__(256) void gnn_gemm(const float* __restrict__ A, const float* __restrict__ W,
                                                const float* __restrict__ bias, float* __restrict__ C,
                                                int K, int OUT) {
  __shared__ float AsT[16][68];   // [k][row]
  __shared__ float Ws[16][68];    // [k][col]
  const int tid = threadIdx.x;
  const int tx = tid & 15, ty = tid >> 4;
  const long row0 = (long)blockIdx.y * 64;
  const int col0 = blockIdx.x * 64;
  const int lr  = tid >> 2;
  const int lk4 = (tid & 3) * 4;
  const int wk  = tid >> 4;
  const int wj4 = (tid & 15) * 4;
  float acc[16];
#pragma unroll
  for (int i = 0; i < 16; ++i) acc[i] = 0.f;

  for (int kc = 0; kc < K; kc += 16) {
    float4 a = *(const float4*)(A + (row0 + lr) * K + kc + lk4);
    float4 w = *(const float4*)(W + (long)(kc + wk) * OUT + col0 + wj4);
    AsT[lk4 + 0][lr] = a.x; AsT[lk4 + 1][lr] = a.y; AsT[lk4 + 2][lr] = a.z; AsT[lk4 + 3][lr] = a.w;
    *(float4*)(&Ws[wk][wj4]) = w;
    __syncthreads();
#pragma unroll
    for (int k = 0; k < 16; ++k) {
      float4 av = *(const float4*)(&AsT[k][ty * 4]);
      float4 wv = *(const float4*)(&Ws[k][tx * 4]);
      GFMA(0, av.x) GFMA(1, av.y) GFMA(2, av.z) GFMA(3, av.w)
    }
    __syncthreads();
  }
#pragma unroll
  for (int i = 0; i < 4; ++i) {
    long row = row0 + ty * 4 + i;
    const float* bp = (BMODE == 0) ? bias : (bias + (row >> 12) * OUT);
    int j = col0 + tx * 4;
    float4 o;
    o.x = acc[i * 4 + 0] + bp[j + 0];
    o.y = acc[i * 4 + 1] + bp[j + 1];
    o.z = acc[i * 4 + 2] + bp[j + 2];
    o.w = acc[i * 4 + 3] + bp[j + 3];
    if (ACT) { o.x = fmaxf(o.x, 0.f); o.y = fmaxf(o.y, 0.f); o.z = fmaxf(o.z, 0.f); o.w = fmaxf(o.w, 0.f); }
    *(float4*)(C + row * OUT + j) = o;
  }
}
#undef GFMA

// ============================================================================
// head: pool, per-graph bias, item-value init, final bound reduction
// ============================================================================
__global__ __launch_bounds__(128) void gnn_pool(const float* __restrict__ X3, float* __restrict__ ge) {
  int b = blockIdx.x >> 3, chunk = blockIdx.x & 7, t = threadIdx.x;
  long base = ((long)b * PP + chunk * 512) * H;
  float acc = 0.f;
  for (int p = 0; p < 512; ++p) acc += X3[base + (long)p * H + t];
  atomicAdd(&ge[b * H + t], acc);
}

__global__ __launch_bounds__(256) void gnn_gbias(const float* __restrict__ ge, const float* __restrict__ Wl1b,
                                                 const float* __restrict__ bl1, float* __restrict__ gb) {
  __shared__ float g[128];
  int b = blockIdx.x, t = threadIdx.x;
  if (t < 128) g[t] = ge[b * H + t] * (1.f / 4096.f);
  __syncthreads();
  float acc = bl1[t];
  for (int k = 0; k < 128; ++k) acc = fmaf(g[k], Wl1b[k * 256 + t], acc);
  gb[b * 256 + t] = acc;
}

__global__ __launch_bounds__(256) void gnn_item(const float* __restrict__ iv, const int* __restrict__ vvs,
                                                float* __restrict__ out) {
  __shared__ float s[256];
  int b = blockIdx.x, t = threadIdx.x;
  float v = iv[b * 256 + t] * (float)vvs[(long)b * PP + t];   // sol[b,0,n]
  s[t] = v; __syncthreads();
  for (int off = 128; off > 0; off >>= 1) {
    if (t < off) s[t] += s[t + off];
    __syncthreads();
  }
  if (t == 0) out[b] = s[0];
}

__global__ __launch_bounds__(256) void gnn_bound(const float* __restrict__ U2, const float* __restrict__ wl3,
                                                 const float* __restrict__ bl3, const int* __restrict__ vvs,
                                                 float* __restrict__ out) {
  int tid = threadIdx.x;
  int wave = tid >> 6, lane = tid & 63;
  int b = blockIdx.x >> 6;
  long node0 = (long)blockIdx.x * 64 + wave * 16;
  float w0 = wl3[lane], w1 = wl3[64 + lane];
  float bl = bl3[0];
  float acc = 0.f;
  for (int i = 0; i < 16; ++i) {
    long node = node0 + i;
    float p = U2[node * H + lane] * w0 + U2[node * H + 64 + lane] * w1;
#pragma unroll
    for (int off = 32; off > 0; off >>= 1) p += __shfl_down(p, off);
    if (lane == 0) {
      int pp = (int)(node & (PP - 1));
      int m = pp >> 8, n = pp & 255;
      if (m != 0) {
        float dx = (float)(vvs[((long)b << 12) + n] - vvs[((long)b << 12) + pp]);
        acc += (p + bl) * dx;
      }
    }
  }
  __shared__ float s[4];
  if (lane == 0) s[wave] = acc;
  __syncthreads();
  if (tid == 0) atomicAdd(&out[b], s[0] + s[1] + s[2] + s[3]);
}

// ============================================================================
extern "C" void kernel_launch(void* const* d_in, const int* in_sizes, int n_in,
                              void* d_out, int out_size, void* d_ws, size_t ws_size,
                              hipStream_t stream) {
  const float* G      = (const float*)d_in[0];
  const int*   ei     = (const int*)d_in[1];
  const int*   esrc   = ei;
  const int*   edst   = ei + EDGES;
  const float* ew     = (const float*)d_in[2];
  const int*   vvs    = (const int*)d_in[4];
  const float* iv     = (const float*)d_in[5];
  const float* W_emb1 = (const float*)d_in[6];
  const float* b_emb1 = (const float*)d_in[7];
  const float* W_emb2 = (const float*)d_in[8];
  const float* b_emb2 = (const float*)d_in[9];
  const float* c1_W   = (const float*)d_in[10];
  const float* c1_wi  = (const float*)d_in[11];
  const float* c1_wh  = (const float*)d_in[12];
  const float* c1_bi  = (const float*)d_in[13];
  const float* c1_bh  = (const float*)d_in[14];
  const float* c2_W   = (const float*)d_in[15];
  const float* c2_wi  = (const float*)d_in[16];
  const float* c2_wh  = (const float*)d_in[17];
  const float* c2_bi  = (const float*)d_in[18];
  const float* c2_bh  = (const float*)d_in[19];
  const float* W_g1   = (const float*)d_in[20];
  const float* b_g1   = (const float*)d_in[21];
  const float* W_g2   = (const float*)d_in[22];
  const float* b_g2   = (const float*)d_in[23];
  const float* W_l1   = (const float*)d_in[24];
  const float* b_l1   = (const float*)d_in[25];
  const float* W_l2   = (const float*)d_in[26];
  const float* b_l2   = (const float*)d_in[27];
  const float* W_l3   = (const float*)d_in[28];
  const float* b_l3   = (const float*)d_in[29];
  float* out = (float*)d_out;
  (void)in_sizes; (void)n_in; (void)out_size; (void)ws_size;

  // ---- workspace carve ----
  char* wsb = (char*)d_ws;
  size_t off = 0;
  auto carve = [&](size_t bytes) -> char* {
    char* p = wsb + off;
    off += (bytes + 255) & ~(size_t)255;
    return p;
  };
  float* b0     = (float*)carve(sizeof(float) * (size_t)NODES * H);   // b0,b1 contiguous: u1 overlays both
  float* b1     = (float*)carve(sizeof(float) * (size_t)NODES * H);
  float* b2     = (float*)carve(sizeof(float) * (size_t)NODES * H);
  float* Wc     = (float*)carve(sizeof(float) * 4 * H * 384);
  float* whT    = (float*)carve(sizeof(float) * 2 * H * 384);
  unsigned short* pk = (unsigned short*)carve(sizeof(unsigned short) * 507904);
  int*   rowptr = (int*)carve(sizeof(int) * (NODES + 1));
  int*   cnt    = (int*)carve(sizeof(int) * NODES);      // counts, later cursor
  int*   bsum   = (int*)carve(sizeof(int) * 512);
  int*   boff   = (int*)carve(sizeof(int) * 512);
  int*   es     = (int*)carve(sizeof(int) * EDGES);
  float* ewt    = (float*)carve(sizeof(float) * EDGES);
  float* ge     = (float*)carve(sizeof(float) * NB * H);
  float* gb     = (float*)carve(sizeof(float) * NB * 256);

  // packed-weight offsets (halves)
  const long RZ = 65536, AI = 16384, AH = 16384, LYR = RZ + AI + AH;  // 98304/layer
  unsigned short* pkRZ[4]; unsigned short* pkAI[4]; unsigned short* pkAH[4];
  for (int l = 0; l < 4; ++l) {
    pkRZ[l] = pk + l * LYR;
    pkAI[l] = pk + l * LYR + RZ;
    pkAH[l] = pk + l * LYR + RZ + AI;
  }
  unsigned short* pe2 = pk + 4 * LYR;
  unsigned short* pg1 = pe2 + 16384;
  unsigned short* pg2 = pg1 + 16384;
  unsigned short* pl1 = pg2 + 16384;
  unsigned short* pl2 = pl1 + 32768;

  // ---- CSR build ----
  hipMemsetAsync(cnt, 0, sizeof(int) * NODES, stream);
  hipMemsetAsync(ge, 0, sizeof(float) * NB * H, stream);
  gnn_hist<<<EDGES / 256, 256, 0, stream>>>(edst, cnt);
  gnn_scan1<<<512, 256, 0, stream>>>(cnt, rowptr, bsum);
  gnn_scan2<<<1, 512, 0, stream>>>(bsum, boff);
  gnn_scan3<<<512, 256, 0, stream>>>(rowptr, boff);
  hipMemcpyAsync(cnt, rowptr, sizeof(int) * NODES, hipMemcpyDeviceToDevice, stream);  // cursor
  gnn_fill<<<EDGES / 256, 256, 0, stream>>>(esrc, edst, ew, cnt, es, ewt);

  // ---- weight prep: Wc[l] = W[l] @ wi.T ; whT = wh.T ----
  gnn_prep_wc<<<128, 384, 0, stream>>>(c1_W,             c1_wi, Wc + 0 * 128 * 384);
  gnn_prep_wc<<<128, 384, 0, stream>>>(c1_W + 128 * 128, c1_wi, Wc + 1 * 128 * 384);
  gnn_prep_wc<<<128, 384, 0, stream>>>(c2_W,             c2_wi, Wc + 2 * 128 * 384);
  gnn_prep_wc<<<128, 384, 0, stream>>>(c2_W + 128 * 128, c2_wi, Wc + 3 * 128 * 384);
  gnn_prep_whT<<<256, 384, 0, stream>>>(c1_wh, c2_wh, whT);

  // ---- pack weights to MFMA B-frag bf16 ----
  for (int l = 0; l < 4; ++l) {
    const float* Wcl = Wc + (long)l * 128 * 384;
    const float* whl = whT + (long)(l >> 1) * 128 * 384;
    gnn_pack<<<16 * 8, 64, 0, stream>>>(Wcl, whl, 128, 384, 0,   8, pkRZ[l]);   // rz: K=256, N=256
    gnn_pack<<<8 * 4, 64, 0, stream>>>(Wcl, Wcl, 128, 384, 256, 4, pkAI[l]);    // ai: K=128, N=128
    gnn_pack<<<8 * 4, 64, 0, stream>>>(whl, whl, 128, 384, 256, 4, pkAH[l]);    // ah
  }
  gnn_pack<<<8 * 4, 64, 0, stream>>>(W_emb2, W_emb2, 128, 128, 0, 4, pe2);
  gnn_pack<<<8 * 4, 64, 0, stream>>>(W_g1,  W_g1,  128, 128, 0, 4, pg1);
  gnn_pack<<<8 * 4, 64, 0, stream>>>(W_g2,  W_g2,  128, 128, 0, 4, pg2);
  gnn_pack<<<16 * 4, 64, 0, stream>>>(W_l1, W_l1,  128, 256, 0, 4, pl1);        // x-part only (K=128,N=256)
  gnn_pack<<<8 * 8, 64, 0, stream>>>(W_l2,  W_l2,  256, 128, 0, 8, pl2);        // K=256,N=128

  // ---- embeddings ----
  gnn_gemm<1, 0><<<dim3(2, NODES / 64), 256, 0, stream>>>(G, W_emb1, b_emb1, b1, 16, 128);
  gnn_mgemm<128, 128, 1, 0><<<NODES / 64, 256, 0, stream>>>(b1, pe2, b_emb2, b0);

  // ---- conv1 (x in b0) ----
  gnn_agg<<<NODES / 4, 256, 0, stream>>>(b0, rowptr, es, ewt, b1);
  gnn_mgru<0><<<NODES / 64, 256, 0, stream>>>(b1, b0, pkRZ[0], pkAI[0], pkAH[0], c1_bi, c1_bh, b2);
  gnn_agg<<<NODES / 4, 256, 0, stream>>>(b2, rowptr, es, ewt, b1);
  gnn_mgru<1><<<NODES / 64, 256, 0, stream>>>(b1, b2, pkRZ[1], pkAI[1], pkAH[1], c1_bi, c1_bh, b0);

  // ---- conv2 (x in b0) ----
  gnn_agg<<<NODES / 4, 256, 0, stream>>>(b0, rowptr, es, ewt, b1);
  gnn_mgru<0><<<NODES / 64, 256, 0, stream>>>(b1, b0, pkRZ[2], pkAI[2], pkAH[2], c2_bi, c2_bh, b2);
  gnn_agg<<<NODES / 4, 256, 0, stream>>>(b2, rowptr, es, ewt, b1);
  gnn_mgru<1><<<NODES / 64, 256, 0, stream>>>(b1, b2, pkRZ[3], pkAI[3], pkAH[3], c2_bi, c2_bh, b0);

  // ---- head GEMMs ----
  gnn_mgemm<128, 128, 1, 0><<<NODES / 64, 256, 0, stream>>>(b0, pg1, b_g1, b1);
  gnn_mgemm<128, 128, 0, 0><<<NODES / 64, 256, 0, stream>>>(b1, pg2, b_g2, b2);   // x3 in b2

  // ---- pool + per-graph bias (folds ge @ W_l1[128:] + b_l1) ----
  gnn_pool<<<NB * 8, 128, 0, stream>>>(b2, ge);
  gnn_gbias<<<NB, 256, 0, stream>>>(ge, W_l1 + 128 * 256, b_l1, gb);

  // ---- MLP: l1 (graph-bias), l2, l3+reduction ----
  gnn_mgemm<128, 256, 1, 1><<<NODES / 64, 256, 0, stream>>>(b2, pl1, gb, b0);   // u1 in b0(+b1)
  gnn_mgemm<256, 128, 1, 0><<<NODES / 64, 256, 0, stream>>>(b0, pl2, b_l2, b2); // u2 in b2
  gnn_item<<<NB, 256, 0, stream>>>(iv, vvs, out);
  gnn_bound<<<NODES / 64, 256, 0, stream>>>(b2, W_l3, b_l3, vvs, out);
}

// Round 3
// 1645.394 us; speedup vs baseline: 2.2999x; 1.1536x over previous
//
#include <hip/hip_runtime.h>

#define NODES   131072
#define EDGES   2097152
#define H       128
#define NB      32        // graphs
#define PP      4096      // nodes per graph

typedef short bf16x8 __attribute__((ext_vector_type(8)));
typedef float f32x4  __attribute__((ext_vector_type(4)));
typedef unsigned short u16;

// ============================================================================
// CSR build: histogram -> hierarchical exclusive scan -> fill (bucket by dst)
// ============================================================================
__global__ __launch_bounds__(256) void gnn_hist(const int* __restrict__ dst, int* __restrict__ counts) {
  int e = blockIdx.x * 256 + threadIdx.x;
  if (e < EDGES) atomicAdd(&counts[dst[e]], 1);
}

__global__ __launch_bounds__(256) void gnn_scan1(const int* __restrict__ counts,
                                                 int* __restrict__ rowptr, int* __restrict__ bsum) {
  __shared__ int s[256];
  int t = threadIdx.x;
  int i = blockIdx.x * 256 + t;
  int v = counts[i];
  s[t] = v; __syncthreads();
  for (int off = 1; off < 256; off <<= 1) {
    int u = (t >= off) ? s[t - off] : 0;
    __syncthreads();
    s[t] += u;
    __syncthreads();
  }
  rowptr[i] = s[t] - v;            // block-local exclusive
  if (t == 255) bsum[blockIdx.x] = s[255];
}

__global__ __launch_bounds__(512) void gnn_scan2(const int* __restrict__ bsum, int* __restrict__ boff) {
  __shared__ int s[512];
  int t = threadIdx.x;
  int v = bsum[t];
  s[t] = v; __syncthreads();
  for (int off = 1; off < 512; off <<= 1) {
    int u = (t >= off) ? s[t - off] : 0;
    __syncthreads();
    s[t] += u;
    __syncthreads();
  }
  boff[t] = s[t] - v;              // exclusive block offsets
}

__global__ __launch_bounds__(256) void gnn_scan3(int* __restrict__ rowptr, const int* __restrict__ boff) {
  int i = blockIdx.x * 256 + threadIdx.x;
  rowptr[i] += boff[blockIdx.x];
  if (i == 0) rowptr[NODES] = EDGES;
}

__global__ __launch_bounds__(256) void gnn_fill(const int* __restrict__ src, const int* __restrict__ dst,
                                                const float* __restrict__ ew, int* __restrict__ cursor,
                                                int* __restrict__ es, float* __restrict__ ewt) {
  int e = blockIdx.x * 256 + threadIdx.x;
  if (e < EDGES) {
    int d = dst[e];
    int p = atomicAdd(&cursor[d], 1);
    es[p]  = src[e];
    ewt[p] = ew[e];
  }
}

// ============================================================================
// bf16 helpers
// ============================================================================
__device__ __forceinline__ unsigned gnn_pack2bf(float a, float b) {
  union { float f; unsigned u; } x, y; x.f = a; y.f = b;
  unsigned ua = (x.u + 0x7FFFu + ((x.u >> 16) & 1u)) >> 16;
  unsigned ub = (y.u + 0x7FFFu + ((y.u >> 16) & 1u)) >> 16;
  return ua | (ub << 16);
}

__device__ __forceinline__ u16 gnn_f2bf(float a) {
  union { float f; unsigned u; } x; x.f = a;
  return (u16)((x.u + 0x7FFFu + ((x.u >> 16) & 1u)) >> 16);
}

__device__ __forceinline__ float gnn_bf2f(u16 h) {
  union { unsigned u; float f; } x; x.u = ((unsigned)h) << 16; return x.f;
}

__device__ __forceinline__ float gnn_sig(float x)  { return 1.f / (1.f + __expf(-x)); }
__device__ __forceinline__ float gnn_tanh(float x) { return 1.f - 2.f / (1.f + __expf(2.f * x)); }

// ============================================================================
// t[i,:] = sum_{e in CSR[i]} ew_e * x[src_e,:]   (one wave per node, bf16 x)
// lane covers cols {2*lane, 2*lane+1}; one 256B row read per edge
// ============================================================================
__global__ __launch_bounds__(256) void gnn_agg(const u16* __restrict__ X, const int* __restrict__ rowptr,
                                               const int* __restrict__ es, const float* __restrict__ ewt,
                                               u16* __restrict__ T) {
  int wave = threadIdx.x >> 6, lane = threadIdx.x & 63;
  long node = (long)blockIdx.x * 4 + wave;
  int e0 = rowptr[node], e1 = rowptr[node + 1];
  float a0 = 0.f, a1 = 0.f;
  for (int e = e0; e < e1; ++e) {
    int s = es[e];
    float w = ewt[e];
    unsigned p = *(const unsigned*)(X + (long)s * H + lane * 2);
    union { unsigned u; float f; } lo, hi;
    lo.u = p << 16; hi.u = p & 0xFFFF0000u;
    a0 = fmaf(w, lo.f, a0);
    a1 = fmaf(w, hi.f, a1);
  }
  *(unsigned*)(T + node * H + lane * 2) = gnn_pack2bf(a0, a1);
}

// ============================================================================
// weight prep: Wc = W[l] @ wi.T  (128x384), whT = wh.T (128x384)
// ============================================================================
__global__ __launch_bounds__(384) void gnn_prep_wc(const float* __restrict__ Wl, const float* __restrict__ wi,
                                                   float* __restrict__ Wc) {
  __shared__ float wrow[128];
  int k = blockIdx.x, j = threadIdx.x;
  if (j < 128) wrow[j] = Wl[k * 128 + j];
  __syncthreads();
  float acc = 0.f;
  for (int m = 0; m < 128; ++m) acc = fmaf(wrow[m], wi[j * 128 + m], acc);
  Wc[k * 384 + j] = acc;
}

__global__ __launch_bounds__(384) void gnn_prep_whT(const float* __restrict__ wh1, const float* __restrict__ wh2,
                                                    float* __restrict__ whT) {
  int c = blockIdx.x >> 7, k = blockIdx.x & 127, j = threadIdx.x;
  const float* wh = c ? wh2 : wh1;
  whT[((long)c * 128 + k) * 384 + j] = wh[j * 128 + k];
}

// ============================================================================
// MFMA fragment plumbing
// A-frag layout (16x16x32): A[m=lane&15][k=(lane>>4)*8+j]
// B-frag layout:            B[k=(lane>>4)*8+j][n=lane&15]
// C/D layout:               col=lane&15, row=(lane>>4)*4+reg
// LDS A staging: slot(ktq,row) = ktq*64 + (row ^ (ktq&7)), 16B per slot
// ============================================================================
template<int K>
__device__ __forceinline__ void gnn_stage_bf(const u16* __restrict__ A, long row0,
                                             u16* lds, int tid) {
  constexpr int CH = K / 8;     // 16B chunks per row
#pragma unroll
  for (int it = 0; it < (64 * CH) / 256; ++it) {
    int c = it * 256 + tid;
    int row = c / CH, ktq = c % CH;
    uint4 v = *(const uint4*)(A + (row0 + row) * K + ktq * 8);
    int slot = ktq * 64 + (row ^ (ktq & 7));
    *(uint4*)(lds + slot * 8) = v;
  }
}

__device__ __forceinline__ bf16x8 gnn_afrag(const u16* lds, int rt, int ktq, int l16) {
  int slot = ktq * 64 + ((rt * 16 + l16) ^ (ktq & 7));
  return *(const bf16x8*)(lds + slot * 8);
}

__device__ __forceinline__ bf16x8 gnn_bfrag(const u16* __restrict__ pk,
                                            int ct, int kt, int KT, int lane) {
  return *(const bf16x8*)(pk + (((long)(ct * KT + kt)) * 64 + lane) * 8);
}

// pack fp32 weight into B-fragment bf16 layout: dst frag (ct,kt) at [(ct*KT+kt)*64+lane]*8 halves
// source element: k<ksplit ? W0[k*LD + coff + col] : W1[(k-ksplit)*LD + coff + col]
__global__ __launch_bounds__(64) void gnn_pack(const float* __restrict__ W0, const float* __restrict__ W1,
                                               int ksplit, int LD, int coff, int KT,
                                               u16* __restrict__ dst) {
  int b = blockIdx.x;
  int kt = b % KT, ct = b / KT;
  int lane = threadIdx.x;
  int col = ct * 16 + (lane & 15) + coff;
  int kb = kt * 32 + ((lane >> 4) & 3) * 8;
  u16 h[8];
#pragma unroll
  for (int j = 0; j < 8; ++j) {
    int k = kb + j;
    float v = (k < ksplit) ? W0[(long)k * LD + col] : W1[(long)(k - ksplit) * LD + col];
    h[j] = gnn_f2bf(v);
  }
  uint4 o;
  o.x = (unsigned)h[0] | ((unsigned)h[1] << 16);
  o.y = (unsigned)h[2] | ((unsigned)h[3] << 16);
  o.z = (unsigned)h[4] | ((unsigned)h[5] << 16);
  o.w = (unsigned)h[6] | ((unsigned)h[7] << 16);
  ((uint4*)dst)[(long)b * 64 + lane] = o;
}

// ============================================================================
// MFMA GEMM: C[M x N] = act(A[M x K] @ Wpk + bias), 64-row blocks, 256 thr.
// A bf16, C bf16. wave w covers cols [w*N/4,...). BMODE 0: bias[j]; 1: per-graph
// ============================================================================
template<int K, int N, int ACT, int BMODE>
__global__ __launch_bounds__(256) void gnn_mgemm(const u16* __restrict__ A,
                                                 const u16* __restrict__ pk,
                                                 const float* __restrict__ bias,
                                                 u16* __restrict__ C) {
  constexpr int KT = K / 32;
  constexpr int CT = N / 64;       // col-tiles per wave
  __shared__ u16 As[64 * K];
  const int tid = threadIdx.x;
  const int lane = tid & 63, wave = tid >> 6;
  const int quad = lane >> 4, l16 = lane & 15;
  const long row0 = (long)blockIdx.x * 64;
  gnn_stage_bf<K>(A, row0, As, tid);
  __syncthreads();

  f32x4 zero4 = {0.f, 0.f, 0.f, 0.f};
  f32x4 acc[4][CT];
#pragma unroll
  for (int rt = 0; rt < 4; ++rt)
#pragma unroll
    for (int ct = 0; ct < CT; ++ct) acc[rt][ct] = zero4;

#pragma unroll
  for (int kt = 0; kt < KT; ++kt) {
    int ktq = kt * 4 + quad;
    bf16x8 af[4];
#pragma unroll
    for (int rt = 0; rt < 4; ++rt) af[rt] = gnn_afrag(As, rt, ktq, l16);
#pragma unroll
    for (int ct = 0; ct < CT; ++ct) {
      bf16x8 bf = gnn_bfrag(pk, wave * CT + ct, kt, KT, lane);
#pragma unroll
      for (int rt = 0; rt < 4; ++rt)
        acc[rt][ct] = __builtin_amdgcn_mfma_f32_16x16x32_bf16(af[rt], bf, acc[rt][ct], 0, 0, 0);
    }
  }

  const float* bp = (BMODE == 0) ? bias : (bias + (row0 >> 12) * N);
#pragma unroll
  for (int ct = 0; ct < CT; ++ct) {
    int col = (wave * CT + ct) * 16 + l16;
    float bv = bp[col];
#pragma unroll
    for (int rt = 0; rt < 4; ++rt) {
      long row = row0 + rt * 16 + quad * 4;
#pragma unroll
      for (int r = 0; r < 4; ++r) {
        float v = acc[rt][ct][r] + bv;
        if (ACT) v = fmaxf(v, 0.f);
        C[(row + r) * N + col] = gnn_f2bf(v);
      }
    }
  }
}

// ============================================================================
// MFMA GRU: Y = GRUCell(m = T@Wc, h = X), all node tensors bf16.
// 64-row blocks, 256 threads; wave w covers gate cols [w*32, w*32+32).
// pkRZ: [256k x 256col] (r cols 0..127, z 128..255); pkAI/pkAH: [128 x 128]
// ============================================================================
template<int RELU>
__global__ __launch_bounds__(256) void gnn_mgru(const u16* __restrict__ T, const u16* __restrict__ X,
                                                const u16* __restrict__ pkRZ,
                                                const u16* __restrict__ pkAI,
                                                const u16* __restrict__ pkAH,
                                                const float* __restrict__ bi, const float* __restrict__ bh,
                                                u16* __restrict__ Y) {
  __shared__ u16 Ts[64 * 128];
  __shared__ u16 Xs[64 * 128];
  const int tid = threadIdx.x;
  const int lane = tid & 63, wave = tid >> 6;
  const int quad = lane >> 4, l16 = lane & 15;
  const long row0 = (long)blockIdx.x * 64;
  gnn_stage_bf<128>(T, row0, Ts, tid);
  gnn_stage_bf<128>(X, row0, Xs, tid);
  __syncthreads();

  f32x4 zero4 = {0.f, 0.f, 0.f, 0.f};
  f32x4 ai[4][2], ah[4][2], rr[4][2];
#pragma unroll
  for (int rt = 0; rt < 4; ++rt)
#pragma unroll
    for (int c = 0; c < 2; ++c) { ai[rt][c] = zero4; ah[rt][c] = zero4; rr[rt][c] = zero4; }

  // fused K-loop: ai (T), ah (X), r (T,X)
#pragma unroll
  for (int kt = 0; kt < 4; ++kt) {
    int ktq = kt * 4 + quad;
    bf16x8 tf[4], xf[4];
#pragma unroll
    for (int rt = 0; rt < 4; ++rt) { tf[rt] = gnn_afrag(Ts, rt, ktq, l16); xf[rt] = gnn_afrag(Xs, rt, ktq, l16); }
#pragma unroll
    for (int c = 0; c < 2; ++c) {
      int ct = wave * 2 + c;
      bf16x8 bAI = gnn_bfrag(pkAI, ct, kt, 4, lane);
      bf16x8 bAH = gnn_bfrag(pkAH, ct, kt, 4, lane);
      bf16x8 bRT = gnn_bfrag(pkRZ, ct, kt,     8, lane);
      bf16x8 bRX = gnn_bfrag(pkRZ, ct, kt + 4, 8, lane);
#pragma unroll
      for (int rt = 0; rt < 4; ++rt) {
        ai[rt][c] = __builtin_amdgcn_mfma_f32_16x16x32_bf16(tf[rt], bAI, ai[rt][c], 0, 0, 0);
        ah[rt][c] = __builtin_amdgcn_mfma_f32_16x16x32_bf16(xf[rt], bAH, ah[rt][c], 0, 0, 0);
        rr[rt][c] = __builtin_amdgcn_mfma_f32_16x16x32_bf16(tf[rt], bRT, rr[rt][c], 0, 0, 0);
        rr[rt][c] = __builtin_amdgcn_mfma_f32_16x16x32_bf16(xf[rt], bRX, rr[rt][c], 0, 0, 0);
      }
    }
  }

  // biases for this lane's two gate columns
  float brz[2], bzz[2], bin_[2], bhn[2];
#pragma unroll
  for (int c = 0; c < 2; ++c) {
    int col = (wave * 2 + c) * 16 + l16;
    brz[c]  = bi[col] + bh[col];
    bzz[c]  = bi[128 + col] + bh[128 + col];
    bin_[c] = bi[256 + col];
    bhn[c]  = bh[256 + col];
  }

  // n = tanh(ai + bi_n + r*(ah + bh_n))   (n overwrites ai)
#pragma unroll
  for (int rt = 0; rt < 4; ++rt)
#pragma unroll
    for (int c = 0; c < 2; ++c)
#pragma unroll
      for (int r = 0; r < 4; ++r) {
        float rv = gnn_sig(rr[rt][c][r] + brz[c]);
        ai[rt][c][r] = gnn_tanh(ai[rt][c][r] + bin_[c] + rv * (ah[rt][c][r] + bhn[c]));
      }

  // z gate
  f32x4 zz[4][2];
#pragma unroll
  for (int rt = 0; rt < 4; ++rt)
#pragma unroll
    for (int c = 0; c < 2; ++c) zz[rt][c] = zero4;
#pragma unroll
  for (int kt = 0; kt < 4; ++kt) {
    int ktq = kt * 4 + quad;
    bf16x8 tf[4], xf[4];
#pragma unroll
    for (int rt = 0; rt < 4; ++rt) { tf[rt] = gnn_afrag(Ts, rt, ktq, l16); xf[rt] = gnn_afrag(Xs, rt, ktq, l16); }
#pragma unroll
    for (int c = 0; c < 2; ++c) {
      int ct = wave * 2 + c;
      bf16x8 bZT = gnn_bfrag(pkRZ, 8 + ct, kt,     8, lane);
      bf16x8 bZX = gnn_bfrag(pkRZ, 8 + ct, kt + 4, 8, lane);
#pragma unroll
      for (int rt = 0; rt < 4; ++rt) {
        zz[rt][c] = __builtin_amdgcn_mfma_f32_16x16x32_bf16(tf[rt], bZT, zz[rt][c], 0, 0, 0);
        zz[rt][c] = __builtin_amdgcn_mfma_f32_16x16x32_bf16(xf[rt], bZX, zz[rt][c], 0, 0, 0);
      }
    }
  }

  // combine + store (h read bf16 from global X)
#pragma unroll
  for (int rt = 0; rt < 4; ++rt)
#pragma unroll
    for (int c = 0; c < 2; ++c) {
      int col = (wave * 2 + c) * 16 + l16;
      long rowb = row0 + rt * 16 + quad * 4;
#pragma unroll
      for (int r = 0; r < 4; ++r) {
        float z = gnn_sig(zz[rt][c][r] + bzz[c]);
        float h = gnn_bf2f(X[(rowb + r) * H + col]);
        float v = (1.f - z) * ai[rt][c][r] + z * h;
        if (RELU) v = fmaxf(v, 0.f);
        Y[(rowb + r) * H + col] = gnn_f2bf(v);
      }
    }
}

// ============================================================================
// fp32-input GEMM (emb1, K=16 only), bf16 output
// ============================================================================
#define GFMA(i, av) \
  acc[(i)*4+0] = fmaf((av), wv.x, acc[(i)*4+0]); \
  acc[(i)*4+1] = fmaf((av), wv.y, acc[(i)*4+1]); \
  acc[(i)*4+2] = fmaf((av), wv.z, acc[(i)*4+2]); \
  acc[(i)*4+3] = fmaf((av), wv.w, acc[(i)*4+3]);

__global__ __launch_bounds__(256) void gnn_gemm16(const float* __restrict__ A, const float* __restrict__ W,
                                                  const float* __restrict__ bias, u16* __restrict__ C,
                                                  int OUT) {
  const int K = 16;
  __shared__ float AsT[16][68];   // [k][row]
  __shared__ float Ws[16][68];    // [k][col]
  const int tid = threadIdx.x;
  const int tx = tid & 15, ty = tid >> 4;
  const long row0 = (long)blockIdx.y * 64;
  const int col0 = blockIdx.x * 64;
  const int lr  = tid >> 2;
  const int lk4 = (tid & 3) * 4;
  const int wk  = tid >> 4;
  const int wj4 = (tid & 15) * 4;
  float acc[16];
#pragma unroll
  for (int i = 0; i < 16; ++i) acc[i] = 0.f;

  {
    float4 a = *(const float4*)(A + (row0 + lr) * K + lk4);
    float4 w = *(const float4*)(W + (long)wk * OUT + col0 + wj4);
    AsT[lk4 + 0][lr] = a.x; AsT[lk4 + 1][lr] = a.y; AsT[lk4 + 2][lr] = a.z; AsT[lk4 + 3][lr] = a.w;
    *(float4*)(&Ws[wk][wj4]) = w;
    __syncthreads();
#pragma unroll
    for (int k = 0; k < 16; ++k) {
      float4 av = *(const float4*)(&AsT[k][ty * 4]);
      float4 wv = *(const float4*)(&Ws[k][tx * 4]);
      GFMA(0, av.x) GFMA(1, av.y) GFMA(2, av.z) GFMA(3, av.w)
    }
  }
#pragma unroll
  for (int i = 0; i < 4; ++i) {
    long row = row0 + ty * 4 + i;
    int j = col0 + tx * 4;
    float4 o;
    o.x = fmaxf(acc[i * 4 + 0] + bias[j + 0], 0.f);
    o.y = fmaxf(acc[i * 4 + 1] + bias[j + 1], 0.f);
    o.z = fmaxf(acc[i * 4 + 2] + bias[j + 2], 0.f);
    o.w = fmaxf(acc[i * 4 + 3] + bias[j + 3], 0.f);
    uint2 st;
    st.x = gnn_pack2bf(o.x, o.y);
    st.y = gnn_pack2bf(o.z, o.w);
    *(uint2*)(C + row * OUT + j) = st;
  }
}
#undef GFMA

// ============================================================================
// head: pool, per-graph bias, item-value init, final bound reduction
// ============================================================================
__global__ __launch_bounds__(128) void gnn_pool(const u16* __restrict__ X3, float* __restrict__ ge) {
  int b = blockIdx.x >> 3, chunk = blockIdx.x & 7, t = threadIdx.x;
  long base = ((long)b * PP + chunk * 512) * H;
  float acc = 0.f;
  for (int p = 0; p < 512; ++p) acc += gnn_bf2f(X3[base + (long)p * H + t]);
  atomicAdd(&ge[b * H + t], acc);
}

__global__ __launch_bounds__(256) void gnn_gbias(const float* __restrict__ ge, const float* __restrict__ Wl1b,
                                                 const float* __restrict__ bl1, float* __restrict__ gb) {
  __shared__ float g[128];
  int b = blockIdx.x, t = threadIdx.x;
  if (t < 128) g[t] = ge[b * H + t] * (1.f / 4096.f);
  __syncthreads();
  float acc = bl1[t];
  for (int k = 0; k < 128; ++k) acc = fmaf(g[k], Wl1b[k * 256 + t], acc);
  gb[b * 256 + t] = acc;
}

__global__ __launch_bounds__(256) void gnn_item(const float* __restrict__ iv, const int* __restrict__ vvs,
                                                float* __restrict__ out) {
  __shared__ float s[256];
  int b = blockIdx.x, t = threadIdx.x;
  float v = iv[b * 256 + t] * (float)vvs[(long)b * PP + t];   // sol[b,0,n]
  s[t] = v; __syncthreads();
  for (int off = 128; off > 0; off >>= 1) {
    if (t < off) s[t] += s[t + off];
    __syncthreads();
  }
  if (t == 0) out[b] = s[0];
}

__global__ __launch_bounds__(256) void gnn_bound(const u16* __restrict__ U2, const float* __restrict__ wl3,
                                                 const float* __restrict__ bl3, const int* __restrict__ vvs,
                                                 float* __restrict__ out) {
  int tid = threadIdx.x;
  int wave = tid >> 6, lane = tid & 63;
  int b = blockIdx.x >> 6;
  long node0 = (long)blockIdx.x * 64 + wave * 16;
  float w0 = wl3[lane * 2], w1 = wl3[lane * 2 + 1];
  float bl = bl3[0];
  float acc = 0.f;
  for (int i = 0; i < 16; ++i) {
    long node = node0 + i;
    unsigned pv = *(const unsigned*)(U2 + node * H + lane * 2);
    union { unsigned u; float f; } lo, hi;
    lo.u = pv << 16; hi.u = pv & 0xFFFF0000u;
    float p = lo.f * w0 + hi.f * w1;
#pragma unroll
    for (int off = 32; off > 0; off >>= 1) p += __shfl_down(p, off);
    if (lane == 0) {
      int pp = (int)(node & (PP - 1));
      int m = pp >> 8, n = pp & 255;
      if (m != 0) {
        float dx = (float)(vvs[((long)b << 12) + n] - vvs[((long)b << 12) + pp]);
        acc += (p + bl) * dx;
      }
    }
  }
  __shared__ float s[4];
  if (lane == 0) s[wave] = acc;
  __syncthreads();
  if (tid == 0) atomicAdd(&out[b], s[0] + s[1] + s[2] + s[3]);
}

// ============================================================================
extern "C" void kernel_launch(void* const* d_in, const int* in_sizes, int n_in,
                              void* d_out, int out_size, void* d_ws, size_t ws_size,
                              hipStream_t stream) {
  const float* G      = (const float*)d_in[0];
  const int*   ei     = (const int*)d_in[1];
  const int*   esrc   = ei;
  const int*   edst   = ei + EDGES;
  const float* ew     = (const float*)d_in[2];
  const int*   vvs    = (const int*)d_in[4];
  const float* iv     = (const float*)d_in[5];
  const float* W_emb1 = (const float*)d_in[6];
  const float* b_emb1 = (const float*)d_in[7];
  const float* W_emb2 = (const float*)d_in[8];
  const float* b_emb2 = (const float*)d_in[9];
  const float* c1_W   = (const float*)d_in[10];
  const float* c1_wi  = (const float*)d_in[11];
  const float* c1_wh  = (const float*)d_in[12];
  const float* c1_bi  = (const float*)d_in[13];
  const float* c1_bh  = (const float*)d_in[14];
  const float* c2_W   = (const float*)d_in[15];
  const float* c2_wi  = (const float*)d_in[16];
  const float* c2_wh  = (const float*)d_in[17];
  const float* c2_bi  = (const float*)d_in[18];
  const float* c2_bh  = (const float*)d_in[19];
  const float* W_g1   = (const float*)d_in[20];
  const float* b_g1   = (const float*)d_in[21];
  const float* W_g2   = (const float*)d_in[22];
  const float* b_g2   = (const float*)d_in[23];
  const float* W_l1   = (const float*)d_in[24];
  const float* b_l1   = (const float*)d_in[25];
  const float* W_l2   = (const float*)d_in[26];
  const float* b_l2   = (const float*)d_in[27];
  const float* W_l3   = (const float*)d_in[28];
  const float* b_l3   = (const float*)d_in[29];
  float* out = (float*)d_out;
  (void)in_sizes; (void)n_in; (void)out_size; (void)ws_size;

  // ---- workspace carve (~186 MiB) ----
  char* wsb = (char*)d_ws;
  size_t off = 0;
  auto carve = [&](size_t bytes) -> char* {
    char* p = wsb + off;
    off += (bytes + 255) & ~(size_t)255;
    return p;
  };
  u16*   xa     = (u16*)carve(sizeof(u16) * (size_t)NODES * H);
  u16*   xc     = (u16*)carve(sizeof(u16) * (size_t)NODES * H);
  u16*   tb     = (u16*)carve(sizeof(u16) * (size_t)NODES * H);
  u16*   u1b    = (u16*)carve(sizeof(u16) * (size_t)NODES * 256);
  float* Wc     = (float*)carve(sizeof(float) * 4 * H * 384);
  float* whT    = (float*)carve(sizeof(float) * 2 * H * 384);
  u16*   pk     = (u16*)carve(sizeof(u16) * 507904);
  int*   rowptr = (int*)carve(sizeof(int) * (NODES + 1));
  int*   cnt    = (int*)carve(sizeof(int) * NODES);      // counts, later cursor
  int*   bsum   = (int*)carve(sizeof(int) * 512);
  int*   boff   = (int*)carve(sizeof(int) * 512);
  int*   es     = (int*)carve(sizeof(int) * EDGES);
  float* ewt    = (float*)carve(sizeof(float) * EDGES);
  float* ge     = (float*)carve(sizeof(float) * NB * H);
  float* gb     = (float*)carve(sizeof(float) * NB * 256);

  // packed-weight offsets (halves)
  const long RZ = 65536, AI = 16384, AH = 16384, LYR = RZ + AI + AH;  // 98304/layer
  u16* pkRZ[4]; u16* pkAI[4]; u16* pkAH[4];
  for (int l = 0; l < 4; ++l) {
    pkRZ[l] = pk + l * LYR;
    pkAI[l] = pk + l * LYR + RZ;
    pkAH[l] = pk + l * LYR + RZ + AI;
  }
  u16* pe2 = pk + 4 * LYR;
  u16* pg1 = pe2 + 16384;
  u16* pg2 = pg1 + 16384;
  u16* pl1 = pg2 + 16384;
  u16* pl2 = pl1 + 32768;

  // ---- CSR build ----
  hipMemsetAsync(cnt, 0, sizeof(int) * NODES, stream);
  hipMemsetAsync(ge, 0, sizeof(float) * NB * H, stream);
  gnn_hist<<<EDGES / 256, 256, 0, stream>>>(edst, cnt);
  gnn_scan1<<<512, 256, 0, stream>>>(cnt, rowptr, bsum);
  gnn_scan2<<<1, 512, 0, stream>>>(bsum, boff);
  gnn_scan3<<<512, 256, 0, stream>>>(rowptr, boff);
  hipMemcpyAsync(cnt, rowptr, sizeof(int) * NODES, hipMemcpyDeviceToDevice, stream);  // cursor
  gnn_fill<<<EDGES / 256, 256, 0, stream>>>(esrc, edst, ew, cnt, es, ewt);

  // ---- weight prep: Wc[l] = W[l] @ wi.T ; whT = wh.T ----
  gnn_prep_wc<<<128, 384, 0, stream>>>(c1_W,             c1_wi, Wc + 0 * 128 * 384);
  gnn_prep_wc<<<128, 384, 0, stream>>>(c1_W + 128 * 128, c1_wi, Wc + 1 * 128 * 384);
  gnn_prep_wc<<<128, 384, 0, stream>>>(c2_W,             c2_wi, Wc + 2 * 128 * 384);
  gnn_prep_wc<<<128, 384, 0, stream>>>(c2_W + 128 * 128, c2_wi, Wc + 3 * 128 * 384);
  gnn_prep_whT<<<256, 384, 0, stream>>>(c1_wh, c2_wh, whT);

  // ---- pack weights to MFMA B-frag bf16 ----
  for (int l = 0; l < 4; ++l) {
    const float* Wcl = Wc + (long)l * 128 * 384;
    const float* whl = whT + (long)(l >> 1) * 128 * 384;
    gnn_pack<<<16 * 8, 64, 0, stream>>>(Wcl, whl, 128, 384, 0,   8, pkRZ[l]);   // rz: K=256, N=256
    gnn_pack<<<8 * 4, 64, 0, stream>>>(Wcl, Wcl, 128, 384, 256, 4, pkAI[l]);    // ai: K=128, N=128
    gnn_pack<<<8 * 4, 64, 0, stream>>>(whl, whl, 128, 384, 256, 4, pkAH[l]);    // ah
  }
  gnn_pack<<<8 * 4, 64, 0, stream>>>(W_emb2, W_emb2, 128, 128, 0, 4, pe2);
  gnn_pack<<<8 * 4, 64, 0, stream>>>(W_g1,  W_g1,  128, 128, 0, 4, pg1);
  gnn_pack<<<8 * 4, 64, 0, stream>>>(W_g2,  W_g2,  128, 128, 0, 4, pg2);
  gnn_pack<<<16 * 4, 64, 0, stream>>>(W_l1, W_l1,  128, 256, 0, 4, pl1);        // x-part only (K=128,N=256)
  gnn_pack<<<8 * 8, 64, 0, stream>>>(W_l2,  W_l2,  256, 128, 0, 8, pl2);        // K=256,N=128

  // ---- embeddings: G -> xa -> xc ----
  gnn_gemm16<<<dim3(2, NODES / 64), 256, 0, stream>>>(G, W_emb1, b_emb1, xa, 128);
  gnn_mgemm<128, 128, 1, 0><<<NODES / 64, 256, 0, stream>>>(xa, pe2, b_emb2, xc);

  // ---- conv1 (x in xc) ----
  gnn_agg<<<NODES / 4, 256, 0, stream>>>(xc, rowptr, es, ewt, tb);
  gnn_mgru<0><<<NODES / 64, 256, 0, stream>>>(tb, xc, pkRZ[0], pkAI[0], pkAH[0], c1_bi, c1_bh, xa);
  gnn_agg<<<NODES / 4, 256, 0, stream>>>(xa, rowptr, es, ewt, tb);
  gnn_mgru<1><<<NODES / 64, 256, 0, stream>>>(tb, xa, pkRZ[1], pkAI[1], pkAH[1], c1_bi, c1_bh, xc);

  // ---- conv2 (x in xc) ----
  gnn_agg<<<NODES / 4, 256, 0, stream>>>(xc, rowptr, es, ewt, tb);
  gnn_mgru<0><<<NODES / 64, 256, 0, stream>>>(tb, xc, pkRZ[2], pkAI[2], pkAH[2], c2_bi, c2_bh, xa);
  gnn_agg<<<NODES / 4, 256, 0, stream>>>(xa, rowptr, es, ewt, tb);
  gnn_mgru<1><<<NODES / 64, 256, 0, stream>>>(tb, xa, pkRZ[3], pkAI[3], pkAH[3], c2_bi, c2_bh, xc);

  // ---- head GEMMs: xc -> xa -> tb (x3) ----
  gnn_mgemm<128, 128, 1, 0><<<NODES / 64, 256, 0, stream>>>(xc, pg1, b_g1, xa);
  gnn_mgemm<128, 128, 0, 0><<<NODES / 64, 256, 0, stream>>>(xa, pg2, b_g2, tb);

  // ---- pool + per-graph bias (folds ge @ W_l1[128:] + b_l1) ----
  gnn_pool<<<NB * 8, 128, 0, stream>>>(tb, ge);
  gnn_gbias<<<NB, 256, 0, stream>>>(ge, W_l1 + 128 * 256, b_l1, gb);

  // ---- MLP: l1 (graph-bias), l2, l3+reduction ----
  gnn_mgemm<128, 256, 1, 1><<<NODES / 64, 256, 0, stream>>>(tb, pl1, gb, u1b);
  gnn_mgemm<256, 128, 1, 0><<<NODES / 64, 256, 0, stream>>>(u1b, pl2, b_l2, xa);  // u2 in xa
  gnn_item<<<NB, 256, 0, stream>>>(iv, vvs, out);
  gnn_bound<<<NODES / 64, 256, 0, stream>>>(xa, W_l3, b_l3, vvs, out);
}

// Round 4
// 1174.296 us; speedup vs baseline: 3.2226x; 1.4012x over previous
//
#include <hip/hip_runtime.h>

#define NODES   131072
#define EDGES   2097152
#define H       128
#define NB      32        // graphs
#define PP      4096      // nodes per graph

typedef short bf16x8 __attribute__((ext_vector_type(8)));
typedef float f32x4  __attribute__((ext_vector_type(4)));
typedef unsigned short u16;

// ============================================================================
// CSR build: histogram -> hierarchical exclusive scan -> fill (bucket by dst)
// ============================================================================
__global__ __launch_bounds__(256) void gnn_hist(const int* __restrict__ dst, int* __restrict__ counts) {
  int e = blockIdx.x * 256 + threadIdx.x;
  if (e < EDGES) atomicAdd(&counts[dst[e]], 1);
}

__global__ __launch_bounds__(256) void gnn_scan1(const int* __restrict__ counts,
                                                 int* __restrict__ rowptr, int* __restrict__ bsum) {
  __shared__ int s[256];
  int t = threadIdx.x;
  int i = blockIdx.x * 256 + t;
  int v = counts[i];
  s[t] = v; __syncthreads();
  for (int off = 1; off < 256; off <<= 1) {
    int u = (t >= off) ? s[t - off] : 0;
    __syncthreads();
    s[t] += u;
    __syncthreads();
  }
  rowptr[i] = s[t] - v;            // block-local exclusive
  if (t == 255) bsum[blockIdx.x] = s[255];
}

__global__ __launch_bounds__(512) void gnn_scan2(const int* __restrict__ bsum, int* __restrict__ boff) {
  __shared__ int s[512];
  int t = threadIdx.x;
  int v = bsum[t];
  s[t] = v; __syncthreads();
  for (int off = 1; off < 512; off <<= 1) {
    int u = (t >= off) ? s[t - off] : 0;
    __syncthreads();
    s[t] += u;
    __syncthreads();
  }
  boff[t] = s[t] - v;              // exclusive block offsets
}

__global__ __launch_bounds__(256) void gnn_scan3(int* __restrict__ rowptr, const int* __restrict__ boff) {
  int i = blockIdx.x * 256 + threadIdx.x;
  rowptr[i] += boff[blockIdx.x];
  if (i == 0) rowptr[NODES] = EDGES;
}

// pack (src, weight-bits) into one int2 per edge -> single 8B scalar load in agg
__global__ __launch_bounds__(256) void gnn_fill(const int* __restrict__ src, const int* __restrict__ dst,
                                                const float* __restrict__ ew, int* __restrict__ cursor,
                                                int2* __restrict__ epack) {
  int e = blockIdx.x * 256 + threadIdx.x;
  if (e < EDGES) {
    int d = dst[e];
    int p = atomicAdd(&cursor[d], 1);
    int2 q; q.x = src[e]; q.y = __float_as_int(ew[e]);
    epack[p] = q;
  }
}

// ============================================================================
// bf16 helpers
// ============================================================================
__device__ __forceinline__ unsigned gnn_pack2bf(float a, float b) {
  union { float f; unsigned u; } x, y; x.f = a; y.f = b;
  unsigned ua = (x.u + 0x7FFFu + ((x.u >> 16) & 1u)) >> 16;
  unsigned ub = (y.u + 0x7FFFu + ((y.u >> 16) & 1u)) >> 16;
  return ua | (ub << 16);
}

__device__ __forceinline__ u16 gnn_f2bf(float a) {
  union { float f; unsigned u; } x; x.f = a;
  return (u16)((x.u + 0x7FFFu + ((x.u >> 16) & 1u)) >> 16);
}

__device__ __forceinline__ float gnn_bf2f(u16 h) {
  union { unsigned u; float f; } x; x.u = ((unsigned)h) << 16; return x.f;
}

__device__ __forceinline__ float gnn_sig(float x)  { return 1.f / (1.f + __expf(-x)); }
__device__ __forceinline__ float gnn_tanh(float x) { return 1.f - 2.f / (1.f + __expf(2.f * x)); }

// ============================================================================
// t[i,:] = sum_{e in CSR[i]} ew_e * x[src_e,:]   (one wave per node, bf16 x)
// lane covers cols {2*lane, 2*lane+1}; one 256B coalesced row read per edge.
// 8-wide software pipeline: 8 scalar edge loads, then 8 independent gathers
// in flight, then FMAs. Cascade 8/4/serial for remainder.
// ============================================================================
__global__ __launch_bounds__(256) void gnn_agg(const u16* __restrict__ X, const int* __restrict__ rowptr,
                                               const int2* __restrict__ epack,
                                               u16* __restrict__ T) {
  int wave = threadIdx.x >> 6, lane = threadIdx.x & 63;
  long node = (long)blockIdx.x * 4 + wave;
  int e0 = rowptr[node], e1 = rowptr[node + 1];
  float a0 = 0.f, a1 = 0.f;
  int e = e0;
  for (; e + 8 <= e1; e += 8) {
    int2 q[8];
#pragma unroll
    for (int j = 0; j < 8; ++j) q[j] = epack[e + j];
    unsigned p[8];
#pragma unroll
    for (int j = 0; j < 8; ++j) p[j] = *(const unsigned*)(X + (long)q[j].x * H + lane * 2);
#pragma unroll
    for (int j = 0; j < 8; ++j) {
      float w = __int_as_float(q[j].y);
      union { unsigned u; float f; } lo, hi;
      lo.u = p[j] << 16; hi.u = p[j] & 0xFFFF0000u;
      a0 = fmaf(w, lo.f, a0);
      a1 = fmaf(w, hi.f, a1);
    }
  }
  if (e + 4 <= e1) {
    int2 q[4];
#pragma unroll
    for (int j = 0; j < 4; ++j) q[j] = epack[e + j];
    unsigned p[4];
#pragma unroll
    for (int j = 0; j < 4; ++j) p[j] = *(const unsigned*)(X + (long)q[j].x * H + lane * 2);
#pragma unroll
    for (int j = 0; j < 4; ++j) {
      float w = __int_as_float(q[j].y);
      union { unsigned u; float f; } lo, hi;
      lo.u = p[j] << 16; hi.u = p[j] & 0xFFFF0000u;
      a0 = fmaf(w, lo.f, a0);
      a1 = fmaf(w, hi.f, a1);
    }
    e += 4;
  }
  for (; e < e1; ++e) {
    int2 q = epack[e];
    float w = __int_as_float(q.y);
    unsigned pv = *(const unsigned*)(X + (long)q.x * H + lane * 2);
    union { unsigned u; float f; } lo, hi;
    lo.u = pv << 16; hi.u = pv & 0xFFFF0000u;
    a0 = fmaf(w, lo.f, a0);
    a1 = fmaf(w, hi.f, a1);
  }
  *(unsigned*)(T + node * H + lane * 2) = gnn_pack2bf(a0, a1);
}

// ============================================================================
// weight prep: Wc = W[l] @ wi.T  (128x384), whT = wh.T (128x384)
// ============================================================================
__global__ __launch_bounds__(384) void gnn_prep_wc(const float* __restrict__ Wl, const float* __restrict__ wi,
                                                   float* __restrict__ Wc) {
  __shared__ float wrow[128];
  int k = blockIdx.x, j = threadIdx.x;
  if (j < 128) wrow[j] = Wl[k * 128 + j];
  __syncthreads();
  float acc = 0.f;
  for (int m = 0; m < 128; ++m) acc = fmaf(wrow[m], wi[j * 128 + m], acc);
  Wc[k * 384 + j] = acc;
}

__global__ __launch_bounds__(384) void gnn_prep_whT(const float* __restrict__ wh1, const float* __restrict__ wh2,
                                                    float* __restrict__ whT) {
  int c = blockIdx.x >> 7, k = blockIdx.x & 127, j = threadIdx.x;
  const float* wh = c ? wh2 : wh1;
  whT[((long)c * 128 + k) * 384 + j] = wh[j * 128 + k];
}

// ============================================================================
// MFMA fragment plumbing
// A-frag layout (16x16x32): A[m=lane&15][k=(lane>>4)*8+j]
// B-frag layout:            B[k=(lane>>4)*8+j][n=lane&15]
// C/D layout:               col=lane&15, row=(lane>>4)*4+reg
// LDS A staging: slot(ktq,row) = ktq*64 + (row ^ (ktq&7)), 16B per slot
// ============================================================================
template<int K>
__device__ __forceinline__ void gnn_stage_bf(const u16* __restrict__ A, long row0,
                                             u16* lds, int tid) {
  constexpr int CH = K / 8;     // 16B chunks per row
#pragma unroll
  for (int it = 0; it < (64 * CH) / 256; ++it) {
    int c = it * 256 + tid;
    int row = c / CH, ktq = c % CH;
    uint4 v = *(const uint4*)(A + (row0 + row) * K + ktq * 8);
    int slot = ktq * 64 + (row ^ (ktq & 7));
    *(uint4*)(lds + slot * 8) = v;
  }
}

__device__ __forceinline__ bf16x8 gnn_afrag(const u16* lds, int rt, int ktq, int l16) {
  int slot = ktq * 64 + ((rt * 16 + l16) ^ (ktq & 7));
  return *(const bf16x8*)(lds + slot * 8);
}

__device__ __forceinline__ bf16x8 gnn_bfrag(const u16* __restrict__ pk,
                                            int ct, int kt, int KT, int lane) {
  return *(const bf16x8*)(pk + (((long)(ct * KT + kt)) * 64 + lane) * 8);
}

// pack fp32 weight into B-fragment bf16 layout: dst frag (ct,kt) at [(ct*KT+kt)*64+lane]*8 halves
// source element: k<ksplit ? W0[k*LD + coff + col] : W1[(k-ksplit)*LD + coff + col]
__global__ __launch_bounds__(64) void gnn_pack(const float* __restrict__ W0, const float* __restrict__ W1,
                                               int ksplit, int LD, int coff, int KT,
                                               u16* __restrict__ dst) {
  int b = blockIdx.x;
  int kt = b % KT, ct = b / KT;
  int lane = threadIdx.x;
  int col = ct * 16 + (lane & 15) + coff;
  int kb = kt * 32 + ((lane >> 4) & 3) * 8;
  u16 h[8];
#pragma unroll
  for (int j = 0; j < 8; ++j) {
    int k = kb + j;
    float v = (k < ksplit) ? W0[(long)k * LD + col] : W1[(long)(k - ksplit) * LD + col];
    h[j] = gnn_f2bf(v);
  }
  uint4 o;
  o.x = (unsigned)h[0] | ((unsigned)h[1] << 16);
  o.y = (unsigned)h[2] | ((unsigned)h[3] << 16);
  o.z = (unsigned)h[4] | ((unsigned)h[5] << 16);
  o.w = (unsigned)h[6] | ((unsigned)h[7] << 16);
  ((uint4*)dst)[(long)b * 64 + lane] = o;
}

// ============================================================================
// MFMA GEMM: C[M x N] = act(A[M x K] @ Wpk + bias), 64-row blocks, 256 thr.
// A bf16, C bf16. wave w covers cols [w*N/4,...). BMODE 0: bias[j]; 1: per-graph
// ============================================================================
template<int K, int N, int ACT, int BMODE>
__global__ __launch_bounds__(256) void gnn_mgemm(const u16* __restrict__ A,
                                                 const u16* __restrict__ pk,
                                                 const float* __restrict__ bias,
                                                 u16* __restrict__ C) {
  constexpr int KT = K / 32;
  constexpr int CT = N / 64;       // col-tiles per wave
  __shared__ u16 As[64 * K];
  const int tid = threadIdx.x;
  const int lane = tid & 63, wave = tid >> 6;
  const int quad = lane >> 4, l16 = lane & 15;
  const long row0 = (long)blockIdx.x * 64;
  gnn_stage_bf<K>(A, row0, As, tid);
  __syncthreads();

  f32x4 zero4 = {0.f, 0.f, 0.f, 0.f};
  f32x4 acc[4][CT];
#pragma unroll
  for (int rt = 0; rt < 4; ++rt)
#pragma unroll
    for (int ct = 0; ct < CT; ++ct) acc[rt][ct] = zero4;

#pragma unroll
  for (int kt = 0; kt < KT; ++kt) {
    int ktq = kt * 4 + quad;
    bf16x8 af[4];
#pragma unroll
    for (int rt = 0; rt < 4; ++rt) af[rt] = gnn_afrag(As, rt, ktq, l16);
#pragma unroll
    for (int ct = 0; ct < CT; ++ct) {
      bf16x8 bf = gnn_bfrag(pk, wave * CT + ct, kt, KT, lane);
#pragma unroll
      for (int rt = 0; rt < 4; ++rt)
        acc[rt][ct] = __builtin_amdgcn_mfma_f32_16x16x32_bf16(af[rt], bf, acc[rt][ct], 0, 0, 0);
    }
  }

  const float* bp = (BMODE == 0) ? bias : (bias + (row0 >> 12) * N);
#pragma unroll
  for (int ct = 0; ct < CT; ++ct) {
    int col = (wave * CT + ct) * 16 + l16;
    float bv = bp[col];
#pragma unroll
    for (int rt = 0; rt < 4; ++rt) {
      long row = row0 + rt * 16 + quad * 4;
#pragma unroll
      for (int r = 0; r < 4; ++r) {
        float v = acc[rt][ct][r] + bv;
        if (ACT) v = fmaxf(v, 0.f);
        C[(row + r) * N + col] = gnn_f2bf(v);
      }
    }
  }
}

// ============================================================================
// MFMA GRU: Y = GRUCell(m = T@Wc, h = X), all node tensors bf16.
// 64-row blocks, 256 threads; wave w covers gate cols [w*32, w*32+32).
// pkRZ: [256k x 256col] (r cols 0..127, z 128..255); pkAI/pkAH: [128 x 128]
// ============================================================================
template<int RELU>
__global__ __launch_bounds__(256) void gnn_mgru(const u16* __restrict__ T, const u16* __restrict__ X,
                                                const u16* __restrict__ pkRZ,
                                                const u16* __restrict__ pkAI,
                                                const u16* __restrict__ pkAH,
                                                const float* __restrict__ bi, const float* __restrict__ bh,
                                                u16* __restrict__ Y) {
  __shared__ u16 Ts[64 * 128];
  __shared__ u16 Xs[64 * 128];
  const int tid = threadIdx.x;
  const int lane = tid & 63, wave = tid >> 6;
  const int quad = lane >> 4, l16 = lane & 15;
  const long row0 = (long)blockIdx.x * 64;
  gnn_stage_bf<128>(T, row0, Ts, tid);
  gnn_stage_bf<128>(X, row0, Xs, tid);
  __syncthreads();

  f32x4 zero4 = {0.f, 0.f, 0.f, 0.f};
  f32x4 ai[4][2], ah[4][2], rr[4][2];
#pragma unroll
  for (int rt = 0; rt < 4; ++rt)
#pragma unroll
    for (int c = 0; c < 2; ++c) { ai[rt][c] = zero4; ah[rt][c] = zero4; rr[rt][c] = zero4; }

  // fused K-loop: ai (T), ah (X), r (T,X)
#pragma unroll
  for (int kt = 0; kt < 4; ++kt) {
    int ktq = kt * 4 + quad;
    bf16x8 tf[4], xf[4];
#pragma unroll
    for (int rt = 0; rt < 4; ++rt) { tf[rt] = gnn_afrag(Ts, rt, ktq, l16); xf[rt] = gnn_afrag(Xs, rt, ktq, l16); }
#pragma unroll
    for (int c = 0; c < 2; ++c) {
      int ct = wave * 2 + c;
      bf16x8 bAI = gnn_bfrag(pkAI, ct, kt, 4, lane);
      bf16x8 bAH = gnn_bfrag(pkAH, ct, kt, 4, lane);
      bf16x8 bRT = gnn_bfrag(pkRZ, ct, kt,     8, lane);
      bf16x8 bRX = gnn_bfrag(pkRZ, ct, kt + 4, 8, lane);
#pragma unroll
      for (int rt = 0; rt < 4; ++rt) {
        ai[rt][c] = __builtin_amdgcn_mfma_f32_16x16x32_bf16(tf[rt], bAI, ai[rt][c], 0, 0, 0);
        ah[rt][c] = __builtin_amdgcn_mfma_f32_16x16x32_bf16(xf[rt], bAH, ah[rt][c], 0, 0, 0);
        rr[rt][c] = __builtin_amdgcn_mfma_f32_16x16x32_bf16(tf[rt], bRT, rr[rt][c], 0, 0, 0);
        rr[rt][c] = __builtin_amdgcn_mfma_f32_16x16x32_bf16(xf[rt], bRX, rr[rt][c], 0, 0, 0);
      }
    }
  }

  // biases for this lane's two gate columns
  float brz[2], bzz[2], bin_[2], bhn[2];
#pragma unroll
  for (int c = 0; c < 2; ++c) {
    int col = (wave * 2 + c) * 16 + l16;
    brz[c]  = bi[col] + bh[col];
    bzz[c]  = bi[128 + col] + bh[128 + col];
    bin_[c] = bi[256 + col];
    bhn[c]  = bh[256 + col];
  }

  // n = tanh(ai + bi_n + r*(ah + bh_n))   (n overwrites ai)
#pragma unroll
  for (int rt = 0; rt < 4; ++rt)
#pragma unroll
    for (int c = 0; c < 2; ++c)
#pragma unroll
      for (int r = 0; r < 4; ++r) {
        float rv = gnn_sig(rr[rt][c][r] + brz[c]);
        ai[rt][c][r] = gnn_tanh(ai[rt][c][r] + bin_[c] + rv * (ah[rt][c][r] + bhn[c]));
      }

  // z gate
  f32x4 zz[4][2];
#pragma unroll
  for (int rt = 0; rt < 4; ++rt)
#pragma unroll
    for (int c = 0; c < 2; ++c) zz[rt][c] = zero4;
#pragma unroll
  for (int kt = 0; kt < 4; ++kt) {
    int ktq = kt * 4 + quad;
    bf16x8 tf[4], xf[4];
#pragma unroll
    for (int rt = 0; rt < 4; ++rt) { tf[rt] = gnn_afrag(Ts, rt, ktq, l16); xf[rt] = gnn_afrag(Xs, rt, ktq, l16); }
#pragma unroll
    for (int c = 0; c < 2; ++c) {
      int ct = wave * 2 + c;
      bf16x8 bZT = gnn_bfrag(pkRZ, 8 + ct, kt,     8, lane);
      bf16x8 bZX = gnn_bfrag(pkRZ, 8 + ct, kt + 4, 8, lane);
#pragma unroll
      for (int rt = 0; rt < 4; ++rt) {
        zz[rt][c] = __builtin_amdgcn_mfma_f32_16x16x32_bf16(tf[rt], bZT, zz[rt][c], 0, 0, 0);
        zz[rt][c] = __builtin_amdgcn_mfma_f32_16x16x32_bf16(xf[rt], bZX, zz[rt][c], 0, 0, 0);
      }
    }
  }

  // combine + store (h read bf16 from global X)
#pragma unroll
  for (int rt = 0; rt < 4; ++rt)
#pragma unroll
    for (int c = 0; c < 2; ++c) {
      int col = (wave * 2 + c) * 16 + l16;
      long rowb = row0 + rt * 16 + quad * 4;
#pragma unroll
      for (int r = 0; r < 4; ++r) {
        float z = gnn_sig(zz[rt][c][r] + bzz[c]);
        float h = gnn_bf2f(X[(rowb + r) * H + col]);
        float v = (1.f - z) * ai[rt][c][r] + z * h;
        if (RELU) v = fmaxf(v, 0.f);
        Y[(rowb + r) * H + col] = gnn_f2bf(v);
      }
    }
}

// ============================================================================
// fp32-input GEMM (emb1, K=16 only), bf16 output
// ============================================================================
#define GFMA(i, av) \
  acc[(i)*4+0] = fmaf((av), wv.x, acc[(i)*4+0]); \
  acc[(i)*4+1] = fmaf((av), wv.y, acc[(i)*4+1]); \
  acc[(i)*4+2] = fmaf((av), wv.z, acc[(i)*4+2]); \
  acc[(i)*4+3] = fmaf((av), wv.w, acc[(i)*4+3]);

__global__ __launch_bounds__(256) void gnn_gemm16(const float* __restrict__ A, const float* __restrict__ W,
                                                  const float* __restrict__ bias, u16* __restrict__ C,
                                                  int OUT) {
  const int K = 16;
  __shared__ float AsT[16][68];   // [k][row]
  __shared__ float Ws[16][68];    // [k][col]
  const int tid = threadIdx.x;
  const int tx = tid & 15, ty = tid >> 4;
  const long row0 = (long)blockIdx.y * 64;
  const int col0 = blockIdx.x * 64;
  const int lr  = tid >> 2;
  const int lk4 = (tid & 3) * 4;
  const int wk  = tid >> 4;
  const int wj4 = (tid & 15) * 4;
  float acc[16];
#pragma unroll
  for (int i = 0; i < 16; ++i) acc[i] = 0.f;

  {
    float4 a = *(const float4*)(A + (row0 + lr) * K + lk4);
    float4 w = *(const float4*)(W + (long)wk * OUT + col0 + wj4);
    AsT[lk4 + 0][lr] = a.x; AsT[lk4 + 1][lr] = a.y; AsT[lk4 + 2][lr] = a.z; AsT[lk4 + 3][lr] = a.w;
    *(float4*)(&Ws[wk][wj4]) = w;
    __syncthreads();
#pragma unroll
    for (int k = 0; k < 16; ++k) {
      float4 av = *(const float4*)(&AsT[k][ty * 4]);
      float4 wv = *(const float4*)(&Ws[k][tx * 4]);
      GFMA(0, av.x) GFMA(1, av.y) GFMA(2, av.z) GFMA(3, av.w)
    }
  }
#pragma unroll
  for (int i = 0; i < 4; ++i) {
    long row = row0 + ty * 4 + i;
    int j = col0 + tx * 4;
    float4 o;
    o.x = fmaxf(acc[i * 4 + 0] + bias[j + 0], 0.f);
    o.y = fmaxf(acc[i * 4 + 1] + bias[j + 1], 0.f);
    o.z = fmaxf(acc[i * 4 + 2] + bias[j + 2], 0.f);
    o.w = fmaxf(acc[i * 4 + 3] + bias[j + 3], 0.f);
    uint2 st;
    st.x = gnn_pack2bf(o.x, o.y);
    st.y = gnn_pack2bf(o.z, o.w);
    *(uint2*)(C + row * OUT + j) = st;
  }
}
#undef GFMA

// ============================================================================
// head: pool, per-graph bias, item-value init, final bound reduction
// ============================================================================
__global__ __launch_bounds__(128) void gnn_pool(const u16* __restrict__ X3, float* __restrict__ ge) {
  int b = blockIdx.x >> 3, chunk = blockIdx.x & 7, t = threadIdx.x;
  long base = ((long)b * PP + chunk * 512) * H;
  float acc = 0.f;
  for (int p = 0; p < 512; ++p) acc += gnn_bf2f(X3[base + (long)p * H + t]);
  atomicAdd(&ge[b * H + t], acc);
}

__global__ __launch_bounds__(256) void gnn_gbias(const float* __restrict__ ge, const float* __restrict__ Wl1b,
                                                 const float* __restrict__ bl1, float* __restrict__ gb) {
  __shared__ float g[128];
  int b = blockIdx.x, t = threadIdx.x;
  if (t < 128) g[t] = ge[b * H + t] * (1.f / 4096.f);
  __syncthreads();
  float acc = bl1[t];
  for (int k = 0; k < 128; ++k) acc = fmaf(g[k], Wl1b[k * 256 + t], acc);
  gb[b * 256 + t] = acc;
}

__global__ __launch_bounds__(256) void gnn_item(const float* __restrict__ iv, const int* __restrict__ vvs,
                                                float* __restrict__ out) {
  __shared__ float s[256];
  int b = blockIdx.x, t = threadIdx.x;
  float v = iv[b * 256 + t] * (float)vvs[(long)b * PP + t];   // sol[b,0,n]
  s[t] = v; __syncthreads();
  for (int off = 128; off > 0; off >>= 1) {
    if (t < off) s[t] += s[t + off];
    __syncthreads();
  }
  if (t == 0) out[b] = s[0];
}

__global__ __launch_bounds__(256) void gnn_bound(const u16* __restrict__ U2, const float* __restrict__ wl3,
                                                 const float* __restrict__ bl3, const int* __restrict__ vvs,
                                                 float* __restrict__ out) {
  int tid = threadIdx.x;
  int wave = tid >> 6, lane = tid & 63;
  int b = blockIdx.x >> 6;
  long node0 = (long)blockIdx.x * 64 + wave * 16;
  float w0 = wl3[lane * 2], w1 = wl3[lane * 2 + 1];
  float bl = bl3[0];
  float acc = 0.f;
  for (int i = 0; i < 16; ++i) {
    long node = node0 + i;
    unsigned pv = *(const unsigned*)(U2 + node * H + lane * 2);
    union { unsigned u; float f; } lo, hi;
    lo.u = pv << 16; hi.u = pv & 0xFFFF0000u;
    float p = lo.f * w0 + hi.f * w1;
#pragma unroll
    for (int off = 32; off > 0; off >>= 1) p += __shfl_down(p, off);
    if (lane == 0) {
      int pp = (int)(node & (PP - 1));
      int m = pp >> 8, n = pp & 255;
      if (m != 0) {
        float dx = (float)(vvs[((long)b << 12) + n] - vvs[((long)b << 12) + pp]);
        acc += (p + bl) * dx;
      }
    }
  }
  __shared__ float s[4];
  if (lane == 0) s[wave] = acc;
  __syncthreads();
  if (tid == 0) atomicAdd(&out[b], s[0] + s[1] + s[2] + s[3]);
}

// ============================================================================
extern "C" void kernel_launch(void* const* d_in, const int* in_sizes, int n_in,
                              void* d_out, int out_size, void* d_ws, size_t ws_size,
                              hipStream_t stream) {
  const float* G      = (const float*)d_in[0];
  const int*   ei     = (const int*)d_in[1];
  const int*   esrc   = ei;
  const int*   edst   = ei + EDGES;
  const float* ew     = (const float*)d_in[2];
  const int*   vvs    = (const int*)d_in[4];
  const float* iv     = (const float*)d_in[5];
  const float* W_emb1 = (const float*)d_in[6];
  const float* b_emb1 = (const float*)d_in[7];
  const float* W_emb2 = (const float*)d_in[8];
  const float* b_emb2 = (const float*)d_in[9];
  const float* c1_W   = (const float*)d_in[10];
  const float* c1_wi  = (const float*)d_in[11];
  const float* c1_wh  = (const float*)d_in[12];
  const float* c1_bi  = (const float*)d_in[13];
  const float* c1_bh  = (const float*)d_in[14];
  const float* c2_W   = (const float*)d_in[15];
  const float* c2_wi  = (const float*)d_in[16];
  const float* c2_wh  = (const float*)d_in[17];
  const float* c2_bi  = (const float*)d_in[18];
  const float* c2_bh  = (const float*)d_in[19];
  const float* W_g1   = (const float*)d_in[20];
  const float* b_g1   = (const float*)d_in[21];
  const float* W_g2   = (const float*)d_in[22];
  const float* b_g2   = (const float*)d_in[23];
  const float* W_l1   = (const float*)d_in[24];
  const float* b_l1   = (const float*)d_in[25];
  const float* W_l2   = (const float*)d_in[26];
  const float* b_l2   = (const float*)d_in[27];
  const float* W_l3   = (const float*)d_in[28];
  const float* b_l3   = (const float*)d_in[29];
  float* out = (float*)d_out;
  (void)in_sizes; (void)n_in; (void)out_size; (void)ws_size;

  // ---- workspace carve (~186 MiB) ----
  char* wsb = (char*)d_ws;
  size_t off = 0;
  auto carve = [&](size_t bytes) -> char* {
    char* p = wsb + off;
    off += (bytes + 255) & ~(size_t)255;
    return p;
  };
  u16*   xa     = (u16*)carve(sizeof(u16) * (size_t)NODES * H);
  u16*   xc     = (u16*)carve(sizeof(u16) * (size_t)NODES * H);
  u16*   tb     = (u16*)carve(sizeof(u16) * (size_t)NODES * H);
  u16*   u1b    = (u16*)carve(sizeof(u16) * (size_t)NODES * 256);
  float* Wc     = (float*)carve(sizeof(float) * 4 * H * 384);
  float* whT    = (float*)carve(sizeof(float) * 2 * H * 384);
  u16*   pk     = (u16*)carve(sizeof(u16) * 507904);
  int*   rowptr = (int*)carve(sizeof(int) * (NODES + 1));
  int*   cnt    = (int*)carve(sizeof(int) * NODES);      // counts, later cursor
  int*   bsum   = (int*)carve(sizeof(int) * 512);
  int*   boff   = (int*)carve(sizeof(int) * 512);
  int2*  epack  = (int2*)carve(sizeof(int2) * EDGES);
  float* ge     = (float*)carve(sizeof(float) * NB * H);
  float* gb     = (float*)carve(sizeof(float) * NB * 256);

  // packed-weight offsets (halves)
  const long RZ = 65536, AI = 16384, AH = 16384, LYR = RZ + AI + AH;  // 98304/layer
  u16* pkRZ[4]; u16* pkAI[4]; u16* pkAH[4];
  for (int l = 0; l < 4; ++l) {
    pkRZ[l] = pk + l * LYR;
    pkAI[l] = pk + l * LYR + RZ;
    pkAH[l] = pk + l * LYR + RZ + AI;
  }
  u16* pe2 = pk + 4 * LYR;
  u16* pg1 = pe2 + 16384;
  u16* pg2 = pg1 + 16384;
  u16* pl1 = pg2 + 16384;
  u16* pl2 = pl1 + 32768;

  // ---- CSR build ----
  hipMemsetAsync(cnt, 0, sizeof(int) * NODES, stream);
  hipMemsetAsync(ge, 0, sizeof(float) * NB * H, stream);
  gnn_hist<<<EDGES / 256, 256, 0, stream>>>(edst, cnt);
  gnn_scan1<<<512, 256, 0, stream>>>(cnt, rowptr, bsum);
  gnn_scan2<<<1, 512, 0, stream>>>(bsum, boff);
  gnn_scan3<<<512, 256, 0, stream>>>(rowptr, boff);
  hipMemcpyAsync(cnt, rowptr, sizeof(int) * NODES, hipMemcpyDeviceToDevice, stream);  // cursor
  gnn_fill<<<EDGES / 256, 256, 0, stream>>>(esrc, edst, ew, cnt, epack);

  // ---- weight prep: Wc[l] = W[l] @ wi.T ; whT = wh.T ----
  gnn_prep_wc<<<128, 384, 0, stream>>>(c1_W,             c1_wi, Wc + 0 * 128 * 384);
  gnn_prep_wc<<<128, 384, 0, stream>>>(c1_W + 128 * 128, c1_wi, Wc + 1 * 128 * 384);
  gnn_prep_wc<<<128, 384, 0, stream>>>(c2_W,             c2_wi, Wc + 2 * 128 * 384);
  gnn_prep_wc<<<128, 384, 0, stream>>>(c2_W + 128 * 128, c2_wi, Wc + 3 * 128 * 384);
  gnn_prep_whT<<<256, 384, 0, stream>>>(c1_wh, c2_wh, whT);

  // ---- pack weights to MFMA B-frag bf16 ----
  for (int l = 0; l < 4; ++l) {
    const float* Wcl = Wc + (long)l * 128 * 384;
    const float* whl = whT + (long)(l >> 1) * 128 * 384;
    gnn_pack<<<16 * 8, 64, 0, stream>>>(Wcl, whl, 128, 384, 0,   8, pkRZ[l]);   // rz: K=256, N=256
    gnn_pack<<<8 * 4, 64, 0, stream>>>(Wcl, Wcl, 128, 384, 256, 4, pkAI[l]);    // ai: K=128, N=128
    gnn_pack<<<8 * 4, 64, 0, stream>>>(whl, whl, 128, 384, 256, 4, pkAH[l]);    // ah
  }
  gnn_pack<<<8 * 4, 64, 0, stream>>>(W_emb2, W_emb2, 128, 128, 0, 4, pe2);
  gnn_pack<<<8 * 4, 64, 0, stream>>>(W_g1,  W_g1,  128, 128, 0, 4, pg1);
  gnn_pack<<<8 * 4, 64, 0, stream>>>(W_g2,  W_g2,  128, 128, 0, 4, pg2);
  gnn_pack<<<16 * 4, 64, 0, stream>>>(W_l1, W_l1,  128, 256, 0, 4, pl1);        // x-part only (K=128,N=256)
  gnn_pack<<<8 * 8, 64, 0, stream>>>(W_l2,  W_l2,  256, 128, 0, 8, pl2);        // K=256,N=128

  // ---- embeddings: G -> xa -> xc ----
  gnn_gemm16<<<dim3(2, NODES / 64), 256, 0, stream>>>(G, W_emb1, b_emb1, xa, 128);
  gnn_mgemm<128, 128, 1, 0><<<NODES / 64, 256, 0, stream>>>(xa, pe2, b_emb2, xc);

  // ---- conv1 (x in xc) ----
  gnn_agg<<<NODES / 4, 256, 0, stream>>>(xc, rowptr, epack, tb);
  gnn_mgru<0><<<NODES / 64, 256, 0, stream>>>(tb, xc, pkRZ[0], pkAI[0], pkAH[0], c1_bi, c1_bh, xa);
  gnn_agg<<<NODES / 4, 256, 0, stream>>>(xa, rowptr, epack, tb);
  gnn_mgru<1><<<NODES / 64, 256, 0, stream>>>(tb, xa, pkRZ[1], pkAI[1], pkAH[1], c1_bi, c1_bh, xc);

  // ---- conv2 (x in xc) ----
  gnn_agg<<<NODES / 4, 256, 0, stream>>>(xc, rowptr, epack, tb);
  gnn_mgru<0><<<NODES / 64, 256, 0, stream>>>(tb, xc, pkRZ[2], pkAI[2], pkAH[2], c2_bi, c2_bh, xa);
  gnn_agg<<<NODES / 4, 256, 0, stream>>>(xa, rowptr, epack, tb);
  gnn_mgru<1><<<NODES / 64, 256, 0, stream>>>(tb, xa, pkRZ[3], pkAI[3], pkAH[3], c2_bi, c2_bh, xc);

  // ---- head GEMMs: xc -> xa -> tb (x3) ----
  gnn_mgemm<128, 128, 1, 0><<<NODES / 64, 256, 0, stream>>>(xc, pg1, b_g1, xa);
  gnn_mgemm<128, 128, 0, 0><<<NODES / 64, 256, 0, stream>>>(xa, pg2, b_g2, tb);

  // ---- pool + per-graph bias (folds ge @ W_l1[128:] + b_l1) ----
  gnn_pool<<<NB * 8, 128, 0, stream>>>(tb, ge);
  gnn_gbias<<<NB, 256, 0, stream>>>(ge, W_l1 + 128 * 256, b_l1, gb);

  // ---- MLP: l1 (graph-bias), l2, l3+reduction ----
  gnn_mgemm<128, 256, 1, 1><<<NODES / 64, 256, 0, stream>>>(tb, pl1, gb, u1b);
  gnn_mgemm<256, 128, 1, 0><<<NODES / 64, 256, 0, stream>>>(u1b, pl2, b_l2, xa);  // u2 in xa
  gnn_item<<<NB, 256, 0, stream>>>(iv, vvs, out);
  gnn_bound<<<NODES / 64, 256, 0, stream>>>(xa, W_l3, b_l3, vvs, out);
}

// Round 5
// 1127.190 us; speedup vs baseline: 3.3573x; 1.0418x over previous
//
#include <hip/hip_runtime.h>

#define NODES   131072
#define EDGES   2097152
#define H       128
#define NB      32        // graphs
#define PP      4096      // nodes per graph

typedef short bf16x8 __attribute__((ext_vector_type(8)));
typedef float f32x4  __attribute__((ext_vector_type(4)));
typedef unsigned short u16;

// ============================================================================
// CSR build: histogram -> hierarchical exclusive scan -> partitioned fill
// ============================================================================
__global__ __launch_bounds__(256) void gnn_hist(const int* __restrict__ dst, int* __restrict__ counts) {
  int e = blockIdx.x * 256 + threadIdx.x;
  if (e < EDGES) atomicAdd(&counts[dst[e]], 1);
}

__global__ __launch_bounds__(256) void gnn_scan1(const int* __restrict__ counts,
                                                 int* __restrict__ rowptr, int* __restrict__ bsum) {
  __shared__ int s[256];
  int t = threadIdx.x;
  int i = blockIdx.x * 256 + t;
  int v = counts[i];
  s[t] = v; __syncthreads();
  for (int off = 1; off < 256; off <<= 1) {
    int u = (t >= off) ? s[t - off] : 0;
    __syncthreads();
    s[t] += u;
    __syncthreads();
  }
  rowptr[i] = s[t] - v;            // block-local exclusive
  if (t == 255) bsum[blockIdx.x] = s[255];
}

__global__ __launch_bounds__(512) void gnn_scan2(const int* __restrict__ bsum, int* __restrict__ boff) {
  __shared__ int s[512];
  int t = threadIdx.x;
  int v = bsum[t];
  s[t] = v; __syncthreads();
  for (int off = 1; off < 512; off <<= 1) {
    int u = (t >= off) ? s[t - off] : 0;
    __syncthreads();
    s[t] += u;
    __syncthreads();
  }
  boff[t] = s[t] - v;              // exclusive block offsets
}

__global__ __launch_bounds__(256) void gnn_scan3(int* __restrict__ rowptr, const int* __restrict__ boff) {
  int i = blockIdx.x * 256 + threadIdx.x;
  rowptr[i] += boff[blockIdx.x];
  if (i == 0) rowptr[NODES] = EDGES;
}

// Partitioned bucket-fill. Partition p owns dst in [p*16384,(p+1)*16384):
// its epack slice is ~1MB -> stays L2-resident while being written, so the
// 64B-sector write-allocate traffic coalesces (round-4 counter showed 8x
// write amplification with unpartitioned scatter).
// Record: src(17b)<<15 | round(ew*32768) (15b fixed point, err<=1.6e-5).
#define FILL_CHUNKS 256
__global__ __launch_bounds__(256) void gnn_fill(const int* __restrict__ src, const int* __restrict__ dst,
                                                const float* __restrict__ ew, int* __restrict__ cursor,
                                                unsigned* __restrict__ epack) {
  const int part  = blockIdx.x >> 8;          // 0..7 (partition-major: window of
  const int chunk = blockIdx.x & 255;         //  co-resident blocks spans ~2 parts)
  const int base  = chunk * (EDGES / FILL_CHUNKS);
#pragma unroll 4
  for (int i = 0; i < (EDGES / FILL_CHUNKS) / 256; ++i) {
    int e = base + i * 256 + threadIdx.x;
    int d = dst[e];
    int s = src[e];
    float w = ew[e];
    if ((d >> 14) == part) {
      int wq = (int)fminf(w * 32768.f + 0.5f, 32767.f);
      int p = atomicAdd(&cursor[d], 1);
      epack[p] = ((unsigned)s << 15) | (unsigned)wq;
    }
  }
}

// ============================================================================
// bf16 helpers
// ============================================================================
__device__ __forceinline__ unsigned gnn_pack2bf(float a, float b) {
  union { float f; unsigned u; } x, y; x.f = a; y.f = b;
  unsigned ua = (x.u + 0x7FFFu + ((x.u >> 16) & 1u)) >> 16;
  unsigned ub = (y.u + 0x7FFFu + ((y.u >> 16) & 1u)) >> 16;
  return ua | (ub << 16);
}

__device__ __forceinline__ u16 gnn_f2bf(float a) {
  union { float f; unsigned u; } x; x.f = a;
  return (u16)((x.u + 0x7FFFu + ((x.u >> 16) & 1u)) >> 16);
}

__device__ __forceinline__ float gnn_bf2f(u16 h) {
  union { unsigned u; float f; } x; x.u = ((unsigned)h) << 16; return x.f;
}

__device__ __forceinline__ float gnn_sig(float x)  { return 1.f / (1.f + __expf(-x)); }
__device__ __forceinline__ float gnn_tanh(float x) { return 1.f - 2.f / (1.f + __expf(2.f * x)); }

// ============================================================================
// t[i,:] = sum_{e in CSR[i]} ew_e * x[src_e,:]   (one wave per node, bf16 x)
// lane covers cols {2*lane, 2*lane+1}; one 256B coalesced row read per edge.
// 16-deep software pipeline (VGPR headroom: round-4 agg used only 12 VGPRs).
// ============================================================================
__device__ __forceinline__ void gnn_agg_edge(const u16* __restrict__ X, unsigned q, int lane,
                                             float& a0, float& a1) {
  unsigned pv = *(const unsigned*)(X + (long)(q >> 15) * H + lane * 2);
  float w = (float)(q & 0x7FFFu) * (1.f / 32768.f);
  union { unsigned u; float f; } lo, hi;
  lo.u = pv << 16; hi.u = pv & 0xFFFF0000u;
  a0 = fmaf(w, lo.f, a0);
  a1 = fmaf(w, hi.f, a1);
}

__global__ __launch_bounds__(256) void gnn_agg(const u16* __restrict__ X, const int* __restrict__ rowptr,
                                               const unsigned* __restrict__ epack,
                                               u16* __restrict__ T) {
  int wave = threadIdx.x >> 6, lane = threadIdx.x & 63;
  long node = (long)blockIdx.x * 4 + wave;
  int e0 = rowptr[node], e1 = rowptr[node + 1];
  float a0 = 0.f, a1 = 0.f;
  int e = e0;
  for (; e + 16 <= e1; e += 16) {
    unsigned q[16];
#pragma unroll
    for (int j = 0; j < 16; ++j) q[j] = epack[e + j];
    unsigned p[16];
#pragma unroll
    for (int j = 0; j < 16; ++j) p[j] = *(const unsigned*)(X + (long)(q[j] >> 15) * H + lane * 2);
#pragma unroll
    for (int j = 0; j < 16; ++j) {
      float w = (float)(q[j] & 0x7FFFu) * (1.f / 32768.f);
      union { unsigned u; float f; } lo, hi;
      lo.u = p[j] << 16; hi.u = p[j] & 0xFFFF0000u;
      a0 = fmaf(w, lo.f, a0);
      a1 = fmaf(w, hi.f, a1);
    }
  }
  if (e + 8 <= e1) {
    unsigned q[8];
#pragma unroll
    for (int j = 0; j < 8; ++j) q[j] = epack[e + j];
    unsigned p[8];
#pragma unroll
    for (int j = 0; j < 8; ++j) p[j] = *(const unsigned*)(X + (long)(q[j] >> 15) * H + lane * 2);
#pragma unroll
    for (int j = 0; j < 8; ++j) {
      float w = (float)(q[j] & 0x7FFFu) * (1.f / 32768.f);
      union { unsigned u; float f; } lo, hi;
      lo.u = p[j] << 16; hi.u = p[j] & 0xFFFF0000u;
      a0 = fmaf(w, lo.f, a0);
      a1 = fmaf(w, hi.f, a1);
    }
    e += 8;
  }
  if (e + 4 <= e1) {
    unsigned q[4];
#pragma unroll
    for (int j = 0; j < 4; ++j) q[j] = epack[e + j];
#pragma unroll
    for (int j = 0; j < 4; ++j) gnn_agg_edge(X, q[j], lane, a0, a1);
    e += 4;
  }
  for (; e < e1; ++e) gnn_agg_edge(X, epack[e], lane, a0, a1);
  *(unsigned*)(T + node * H + lane * 2) = gnn_pack2bf(a0, a1);
}

// ============================================================================
// weight prep: Wc = W[l] @ wi.T  (128x384), whT = wh.T (128x384)
// ============================================================================
__global__ __launch_bounds__(384) void gnn_prep_wc(const float* __restrict__ Wl, const float* __restrict__ wi,
                                                   float* __restrict__ Wc) {
  __shared__ float wrow[128];
  int k = blockIdx.x, j = threadIdx.x;
  if (j < 128) wrow[j] = Wl[k * 128 + j];
  __syncthreads();
  float acc = 0.f;
  for (int m = 0; m < 128; ++m) acc = fmaf(wrow[m], wi[j * 128 + m], acc);
  Wc[k * 384 + j] = acc;
}

__global__ __launch_bounds__(384) void gnn_prep_whT(const float* __restrict__ wh1, const float* __restrict__ wh2,
                                                    float* __restrict__ whT) {
  int c = blockIdx.x >> 7, k = blockIdx.x & 127, j = threadIdx.x;
  const float* wh = c ? wh2 : wh1;
  whT[((long)c * 128 + k) * 384 + j] = wh[j * 128 + k];
}

// ============================================================================
// MFMA fragment plumbing
// A-frag layout (16x16x32): A[m=lane&15][k=(lane>>4)*8+j]
// B-frag layout:            B[k=(lane>>4)*8+j][n=lane&15]
// C/D layout:               col=lane&15, row=(lane>>4)*4+reg
// LDS A staging: slot(ktq,row) = ktq*64 + (row ^ (ktq&7)), 16B per slot
// ============================================================================
template<int K>
__device__ __forceinline__ void gnn_stage_bf(const u16* __restrict__ A, long row0,
                                             u16* lds, int tid) {
  constexpr int CH = K / 8;     // 16B chunks per row
#pragma unroll
  for (int it = 0; it < (64 * CH) / 256; ++it) {
    int c = it * 256 + tid;
    int row = c / CH, ktq = c % CH;
    uint4 v = *(const uint4*)(A + (row0 + row) * K + ktq * 8);
    int slot = ktq * 64 + (row ^ (ktq & 7));
    *(uint4*)(lds + slot * 8) = v;
  }
}

__device__ __forceinline__ bf16x8 gnn_afrag(const u16* lds, int rt, int ktq, int l16) {
  int slot = ktq * 64 + ((rt * 16 + l16) ^ (ktq & 7));
  return *(const bf16x8*)(lds + slot * 8);
}

__device__ __forceinline__ bf16x8 gnn_bfrag(const u16* __restrict__ pk,
                                            int ct, int kt, int KT, int lane) {
  return *(const bf16x8*)(pk + (((long)(ct * KT + kt)) * 64 + lane) * 8);
}

// pack fp32 weight into B-fragment bf16 layout: dst frag (ct,kt) at [(ct*KT+kt)*64+lane]*8 halves
// source element: k<ksplit ? W0[k*LD + coff + col] : W1[(k-ksplit)*LD + coff + col]
__global__ __launch_bounds__(64) void gnn_pack(const float* __restrict__ W0, const float* __restrict__ W1,
                                               int ksplit, int LD, int coff, int KT,
                                               u16* __restrict__ dst) {
  int b = blockIdx.x;
  int kt = b % KT, ct = b / KT;
  int lane = threadIdx.x;
  int col = ct * 16 + (lane & 15) + coff;
  int kb = kt * 32 + ((lane >> 4) & 3) * 8;
  u16 h[8];
#pragma unroll
  for (int j = 0; j < 8; ++j) {
    int k = kb + j;
    float v = (k < ksplit) ? W0[(long)k * LD + col] : W1[(long)(k - ksplit) * LD + col];
    h[j] = gnn_f2bf(v);
  }
  uint4 o;
  o.x = (unsigned)h[0] | ((unsigned)h[1] << 16);
  o.y = (unsigned)h[2] | ((unsigned)h[3] << 16);
  o.z = (unsigned)h[4] | ((unsigned)h[5] << 16);
  o.w = (unsigned)h[6] | ((unsigned)h[7] << 16);
  ((uint4*)dst)[(long)b * 64 + lane] = o;
}

// ============================================================================
// MFMA GEMM: C[M x N] = act(A[M x K] @ Wpk + bias), 64-row blocks, 256 thr.
// A bf16, C bf16. wave w covers cols [w*N/4,...). BMODE 0: bias[j]; 1: per-graph
// ============================================================================
template<int K, int N, int ACT, int BMODE>
__global__ __launch_bounds__(256) void gnn_mgemm(const u16* __restrict__ A,
                                                 const u16* __restrict__ pk,
                                                 const float* __restrict__ bias,
                                                 u16* __restrict__ C) {
  constexpr int KT = K / 32;
  constexpr int CT = N / 64;       // col-tiles per wave
  __shared__ u16 As[64 * K];
  const int tid = threadIdx.x;
  const int lane = tid & 63, wave = tid >> 6;
  const int quad = lane >> 4, l16 = lane & 15;
  const long row0 = (long)blockIdx.x * 64;
  gnn_stage_bf<K>(A, row0, As, tid);
  __syncthreads();

  f32x4 zero4 = {0.f, 0.f, 0.f, 0.f};
  f32x4 acc[4][CT];
#pragma unroll
  for (int rt = 0; rt < 4; ++rt)
#pragma unroll
    for (int ct = 0; ct < CT; ++ct) acc[rt][ct] = zero4;

#pragma unroll
  for (int kt = 0; kt < KT; ++kt) {
    int ktq = kt * 4 + quad;
    bf16x8 af[4];
#pragma unroll
    for (int rt = 0; rt < 4; ++rt) af[rt] = gnn_afrag(As, rt, ktq, l16);
#pragma unroll
    for (int ct = 0; ct < CT; ++ct) {
      bf16x8 bf = gnn_bfrag(pk, wave * CT + ct, kt, KT, lane);
#pragma unroll
      for (int rt = 0; rt < 4; ++rt)
        acc[rt][ct] = __builtin_amdgcn_mfma_f32_16x16x32_bf16(af[rt], bf, acc[rt][ct], 0, 0, 0);
    }
  }

  const float* bp = (BMODE == 0) ? bias : (bias + (row0 >> 12) * N);
#pragma unroll
  for (int ct = 0; ct < CT; ++ct) {
    int col = (wave * CT + ct) * 16 + l16;
    float bv = bp[col];
#pragma unroll
    for (int rt = 0; rt < 4; ++rt) {
      long row = row0 + rt * 16 + quad * 4;
#pragma unroll
      for (int r = 0; r < 4; ++r) {
        float v = acc[rt][ct][r] + bv;
        if (ACT) v = fmaxf(v, 0.f);
        C[(row + r) * N + col] = gnn_f2bf(v);
      }
    }
  }
}

// ============================================================================
// MFMA GRU: Y = GRUCell(m = T@Wc, h = X), all node tensors bf16.
// 64-row blocks, 256 threads; wave w covers gate cols [w*32, w*32+32).
// pkRZ: [256k x 256col] (r cols 0..127, z 128..255); pkAI/pkAH: [128 x 128]
// ============================================================================
template<int RELU>
__global__ __launch_bounds__(256) void gnn_mgru(const u16* __restrict__ T, const u16* __restrict__ X,
                                                const u16* __restrict__ pkRZ,
                                                const u16* __restrict__ pkAI,
                                                const u16* __restrict__ pkAH,
                                                const float* __restrict__ bi, const float* __restrict__ bh,
                                                u16* __restrict__ Y) {
  __shared__ u16 Ts[64 * 128];
  __shared__ u16 Xs[64 * 128];
  const int tid = threadIdx.x;
  const int lane = tid & 63, wave = tid >> 6;
  const int quad = lane >> 4, l16 = lane & 15;
  const long row0 = (long)blockIdx.x * 64;
  gnn_stage_bf<128>(T, row0, Ts, tid);
  gnn_stage_bf<128>(X, row0, Xs, tid);
  __syncthreads();

  f32x4 zero4 = {0.f, 0.f, 0.f, 0.f};
  f32x4 ai[4][2], ah[4][2], rr[4][2];
#pragma unroll
  for (int rt = 0; rt < 4; ++rt)
#pragma unroll
    for (int c = 0; c < 2; ++c) { ai[rt][c] = zero4; ah[rt][c] = zero4; rr[rt][c] = zero4; }

  // fused K-loop: ai (T), ah (X), r (T,X)
#pragma unroll
  for (int kt = 0; kt < 4; ++kt) {
    int ktq = kt * 4 + quad;
    bf16x8 tf[4], xf[4];
#pragma unroll
    for (int rt = 0; rt < 4; ++rt) { tf[rt] = gnn_afrag(Ts, rt, ktq, l16); xf[rt] = gnn_afrag(Xs, rt, ktq, l16); }
#pragma unroll
    for (int c = 0; c < 2; ++c) {
      int ct = wave * 2 + c;
      bf16x8 bAI = gnn_bfrag(pkAI, ct, kt, 4, lane);
      bf16x8 bAH = gnn_bfrag(pkAH, ct, kt, 4, lane);
      bf16x8 bRT = gnn_bfrag(pkRZ, ct, kt,     8, lane);
      bf16x8 bRX = gnn_bfrag(pkRZ, ct, kt + 4, 8, lane);
#pragma unroll
      for (int rt = 0; rt < 4; ++rt) {
        ai[rt][c] = __builtin_amdgcn_mfma_f32_16x16x32_bf16(tf[rt], bAI, ai[rt][c], 0, 0, 0);
        ah[rt][c] = __builtin_amdgcn_mfma_f32_16x16x32_bf16(xf[rt], bAH, ah[rt][c], 0, 0, 0);
        rr[rt][c] = __builtin_amdgcn_mfma_f32_16x16x32_bf16(tf[rt], bRT, rr[rt][c], 0, 0, 0);
        rr[rt][c] = __builtin_amdgcn_mfma_f32_16x16x32_bf16(xf[rt], bRX, rr[rt][c], 0, 0, 0);
      }
    }
  }

  // biases for this lane's two gate columns
  float brz[2], bzz[2], bin_[2], bhn[2];
#pragma unroll
  for (int c = 0; c < 2; ++c) {
    int col = (wave * 2 + c) * 16 + l16;
    brz[c]  = bi[col] + bh[col];
    bzz[c]  = bi[128 + col] + bh[128 + col];
    bin_[c] = bi[256 + col];
    bhn[c]  = bh[256 + col];
  }

  // n = tanh(ai + bi_n + r*(ah + bh_n))   (n overwrites ai)
#pragma unroll
  for (int rt = 0; rt < 4; ++rt)
#pragma unroll
    for (int c = 0; c < 2; ++c)
#pragma unroll
      for (int r = 0; r < 4; ++r) {
        float rv = gnn_sig(rr[rt][c][r] + brz[c]);
        ai[rt][c][r] = gnn_tanh(ai[rt][c][r] + bin_[c] + rv * (ah[rt][c][r] + bhn[c]));
      }

  // z gate
  f32x4 zz[4][2];
#pragma unroll
  for (int rt = 0; rt < 4; ++rt)
#pragma unroll
    for (int c = 0; c < 2; ++c) zz[rt][c] = zero4;
#pragma unroll
  for (int kt = 0; kt < 4; ++kt) {
    int ktq = kt * 4 + quad;
    bf16x8 tf[4], xf[4];
#pragma unroll
    for (int rt = 0; rt < 4; ++rt) { tf[rt] = gnn_afrag(Ts, rt, ktq, l16); xf[rt] = gnn_afrag(Xs, rt, ktq, l16); }
#pragma unroll
    for (int c = 0; c < 2; ++c) {
      int ct = wave * 2 + c;
      bf16x8 bZT = gnn_bfrag(pkRZ, 8 + ct, kt,     8, lane);
      bf16x8 bZX = gnn_bfrag(pkRZ, 8 + ct, kt + 4, 8, lane);
#pragma unroll
      for (int rt = 0; rt < 4; ++rt) {
        zz[rt][c] = __builtin_amdgcn_mfma_f32_16x16x32_bf16(tf[rt], bZT, zz[rt][c], 0, 0, 0);
        zz[rt][c] = __builtin_amdgcn_mfma_f32_16x16x32_bf16(xf[rt], bZX, zz[rt][c], 0, 0, 0);
      }
    }
  }

  // combine + store (h read bf16 from global X)
#pragma unroll
  for (int rt = 0; rt < 4; ++rt)
#pragma unroll
    for (int c = 0; c < 2; ++c) {
      int col = (wave * 2 + c) * 16 + l16;
      long rowb = row0 + rt * 16 + quad * 4;
#pragma unroll
      for (int r = 0; r < 4; ++r) {
        float z = gnn_sig(zz[rt][c][r] + bzz[c]);
        float h = gnn_bf2f(X[(rowb + r) * H + col]);
        float v = (1.f - z) * ai[rt][c][r] + z * h;
        if (RELU) v = fmaxf(v, 0.f);
        Y[(rowb + r) * H + col] = gnn_f2bf(v);
      }
    }
}

// ============================================================================
// fp32-input GEMM (emb1, K=16 only), bf16 output
// ============================================================================
#define GFMA(i, av) \
  acc[(i)*4+0] = fmaf((av), wv.x, acc[(i)*4+0]); \
  acc[(i)*4+1] = fmaf((av), wv.y, acc[(i)*4+1]); \
  acc[(i)*4+2] = fmaf((av), wv.z, acc[(i)*4+2]); \
  acc[(i)*4+3] = fmaf((av), wv.w, acc[(i)*4+3]);

__global__ __launch_bounds__(256) void gnn_gemm16(const float* __restrict__ A, const float* __restrict__ W,
                                                  const float* __restrict__ bias, u16* __restrict__ C,
                                                  int OUT) {
  const int K = 16;
  __shared__ float AsT[16][68];   // [k][row]
  __shared__ float Ws[16][68];    // [k][col]
  const int tid = threadIdx.x;
  const int tx = tid & 15, ty = tid >> 4;
  const long row0 = (long)blockIdx.y * 64;
  const int col0 = blockIdx.x * 64;
  const int lr  = tid >> 2;
  const int lk4 = (tid & 3) * 4;
  const int wk  = tid >> 4;
  const int wj4 = (tid & 15) * 4;
  float acc[16];
#pragma unroll
  for (int i = 0; i < 16; ++i) acc[i] = 0.f;

  {
    float4 a = *(const float4*)(A + (row0 + lr) * K + lk4);
    float4 w = *(const float4*)(W + (long)wk * OUT + col0 + wj4);
    AsT[lk4 + 0][lr] = a.x; AsT[lk4 + 1][lr] = a.y; AsT[lk4 + 2][lr] = a.z; AsT[lk4 + 3][lr] = a.w;
    *(float4*)(&Ws[wk][wj4]) = w;
    __syncthreads();
#pragma unroll
    for (int k = 0; k < 16; ++k) {
      float4 av = *(const float4*)(&AsT[k][ty * 4]);
      float4 wv = *(const float4*)(&Ws[k][tx * 4]);
      GFMA(0, av.x) GFMA(1, av.y) GFMA(2, av.z) GFMA(3, av.w)
    }
  }
#pragma unroll
  for (int i = 0; i < 4; ++i) {
    long row = row0 + ty * 4 + i;
    int j = col0 + tx * 4;
    float4 o;
    o.x = fmaxf(acc[i * 4 + 0] + bias[j + 0], 0.f);
    o.y = fmaxf(acc[i * 4 + 1] + bias[j + 1], 0.f);
    o.z = fmaxf(acc[i * 4 + 2] + bias[j + 2], 0.f);
    o.w = fmaxf(acc[i * 4 + 3] + bias[j + 3], 0.f);
    uint2 st;
    st.x = gnn_pack2bf(o.x, o.y);
    st.y = gnn_pack2bf(o.z, o.w);
    *(uint2*)(C + row * OUT + j) = st;
  }
}
#undef GFMA

// ============================================================================
// head: pool, per-graph bias, item-value init, final bound reduction
// ============================================================================
__global__ __launch_bounds__(128) void gnn_pool(const u16* __restrict__ X3, float* __restrict__ ge) {
  int b = blockIdx.x >> 3, chunk = blockIdx.x & 7, t = threadIdx.x;
  long base = ((long)b * PP + chunk * 512) * H;
  float acc = 0.f;
  for (int p = 0; p < 512; ++p) acc += gnn_bf2f(X3[base + (long)p * H + t]);
  atomicAdd(&ge[b * H + t], acc);
}

__global__ __launch_bounds__(256) void gnn_gbias(const float* __restrict__ ge, const float* __restrict__ Wl1b,
                                                 const float* __restrict__ bl1, float* __restrict__ gb) {
  __shared__ float g[128];
  int b = blockIdx.x, t = threadIdx.x;
  if (t < 128) g[t] = ge[b * H + t] * (1.f / 4096.f);
  __syncthreads();
  float acc = bl1[t];
  for (int k = 0; k < 128; ++k) acc = fmaf(g[k], Wl1b[k * 256 + t], acc);
  gb[b * 256 + t] = acc;
}

__global__ __launch_bounds__(256) void gnn_item(const float* __restrict__ iv, const int* __restrict__ vvs,
                                                float* __restrict__ out) {
  __shared__ float s[256];
  int b = blockIdx.x, t = threadIdx.x;
  float v = iv[b * 256 + t] * (float)vvs[(long)b * PP + t];   // sol[b,0,n]
  s[t] = v; __syncthreads();
  for (int off = 128; off > 0; off >>= 1) {
    if (t < off) s[t] += s[t + off];
    __syncthreads();
  }
  if (t == 0) out[b] = s[0];
}

__global__ __launch_bounds__(256) void gnn_bound(const u16* __restrict__ U2, const float* __restrict__ wl3,
                                                 const float* __restrict__ bl3, const int* __restrict__ vvs,
                                                 float* __restrict__ out) {
  int tid = threadIdx.x;
  int wave = tid >> 6, lane = tid & 63;
  int b = blockIdx.x >> 6;
  long node0 = (long)blockIdx.x * 64 + wave * 16;
  float w0 = wl3[lane * 2], w1 = wl3[lane * 2 + 1];
  float bl = bl3[0];
  float acc = 0.f;
  for (int i = 0; i < 16; ++i) {
    long node = node0 + i;
    unsigned pv = *(const unsigned*)(U2 + node * H + lane * 2);
    union { unsigned u; float f; } lo, hi;
    lo.u = pv << 16; hi.u = pv & 0xFFFF0000u;
    float p = lo.f * w0 + hi.f * w1;
#pragma unroll
    for (int off = 32; off > 0; off >>= 1) p += __shfl_down(p, off);
    if (lane == 0) {
      int pp = (int)(node & (PP - 1));
      int m = pp >> 8, n = pp & 255;
      if (m != 0) {
        float dx = (float)(vvs[((long)b << 12) + n] - vvs[((long)b << 12) + pp]);
        acc += (p + bl) * dx;
      }
    }
  }
  __shared__ float s[4];
  if (lane == 0) s[wave] = acc;
  __syncthreads();
  if (tid == 0) atomicAdd(&out[b], s[0] + s[1] + s[2] + s[3]);
}

// ============================================================================
extern "C" void kernel_launch(void* const* d_in, const int* in_sizes, int n_in,
                              void* d_out, int out_size, void* d_ws, size_t ws_size,
                              hipStream_t stream) {
  const float* G      = (const float*)d_in[0];
  const int*   ei     = (const int*)d_in[1];
  const int*   esrc   = ei;
  const int*   edst   = ei + EDGES;
  const float* ew     = (const float*)d_in[2];
  const int*   vvs    = (const int*)d_in[4];
  const float* iv     = (const float*)d_in[5];
  const float* W_emb1 = (const float*)d_in[6];
  const float* b_emb1 = (const float*)d_in[7];
  const float* W_emb2 = (const float*)d_in[8];
  const float* b_emb2 = (const float*)d_in[9];
  const float* c1_W   = (const float*)d_in[10];
  const float* c1_wi  = (const float*)d_in[11];
  const float* c1_wh  = (const float*)d_in[12];
  const float* c1_bi  = (const float*)d_in[13];
  const float* c1_bh  = (const float*)d_in[14];
  const float* c2_W   = (const float*)d_in[15];
  const float* c2_wi  = (const float*)d_in[16];
  const float* c2_wh  = (const float*)d_in[17];
  const float* c2_bi  = (const float*)d_in[18];
  const float* c2_bh  = (const float*)d_in[19];
  const float* W_g1   = (const float*)d_in[20];
  const float* b_g1   = (const float*)d_in[21];
  const float* W_g2   = (const float*)d_in[22];
  const float* b_g2   = (const float*)d_in[23];
  const float* W_l1   = (const float*)d_in[24];
  const float* b_l1   = (const float*)d_in[25];
  const float* W_l2   = (const float*)d_in[26];
  const float* b_l2   = (const float*)d_in[27];
  const float* W_l3   = (const float*)d_in[28];
  const float* b_l3   = (const float*)d_in[29];
  float* out = (float*)d_out;
  (void)in_sizes; (void)n_in; (void)out_size; (void)ws_size;

  // ---- workspace carve (~178 MiB) ----
  char* wsb = (char*)d_ws;
  size_t off = 0;
  auto carve = [&](size_t bytes) -> char* {
    char* p = wsb + off;
    off += (bytes + 255) & ~(size_t)255;
    return p;
  };
  u16*   xa     = (u16*)carve(sizeof(u16) * (size_t)NODES * H);
  u16*   xc     = (u16*)carve(sizeof(u16) * (size_t)NODES * H);
  u16*   tb     = (u16*)carve(sizeof(u16) * (size_t)NODES * H);
  u16*   u1b    = (u16*)carve(sizeof(u16) * (size_t)NODES * 256);
  float* Wc     = (float*)carve(sizeof(float) * 4 * H * 384);
  float* whT    = (float*)carve(sizeof(float) * 2 * H * 384);
  u16*   pk     = (u16*)carve(sizeof(u16) * 507904);
  int*   rowptr = (int*)carve(sizeof(int) * (NODES + 1));
  int*   cnt    = (int*)carve(sizeof(int) * NODES);      // counts, later cursor
  int*   bsum   = (int*)carve(sizeof(int) * 512);
  int*   boff   = (int*)carve(sizeof(int) * 512);
  unsigned* epack = (unsigned*)carve(sizeof(unsigned) * EDGES);
  float* ge     = (float*)carve(sizeof(float) * NB * H);
  float* gb     = (float*)carve(sizeof(float) * NB * 256);

  // packed-weight offsets (halves)
  const long RZ = 65536, AI = 16384, AH = 16384, LYR = RZ + AI + AH;  // 98304/layer
  u16* pkRZ[4]; u16* pkAI[4]; u16* pkAH[4];
  for (int l = 0; l < 4; ++l) {
    pkRZ[l] = pk + l * LYR;
    pkAI[l] = pk + l * LYR + RZ;
    pkAH[l] = pk + l * LYR + RZ + AI;
  }
  u16* pe2 = pk + 4 * LYR;
  u16* pg1 = pe2 + 16384;
  u16* pg2 = pg1 + 16384;
  u16* pl1 = pg2 + 16384;
  u16* pl2 = pl1 + 32768;

  // ---- CSR build ----
  hipMemsetAsync(cnt, 0, sizeof(int) * NODES, stream);
  hipMemsetAsync(ge, 0, sizeof(float) * NB * H, stream);
  gnn_hist<<<EDGES / 256, 256, 0, stream>>>(edst, cnt);
  gnn_scan1<<<512, 256, 0, stream>>>(cnt, rowptr, bsum);
  gnn_scan2<<<1, 512, 0, stream>>>(bsum, boff);
  gnn_scan3<<<512, 256, 0, stream>>>(rowptr, boff);
  hipMemcpyAsync(cnt, rowptr, sizeof(int) * NODES, hipMemcpyDeviceToDevice, stream);  // cursor
  gnn_fill<<<8 * FILL_CHUNKS, 256, 0, stream>>>(esrc, edst, ew, cnt, epack);

  // ---- weight prep: Wc[l] = W[l] @ wi.T ; whT = wh.T ----
  gnn_prep_wc<<<128, 384, 0, stream>>>(c1_W,             c1_wi, Wc + 0 * 128 * 384);
  gnn_prep_wc<<<128, 384, 0, stream>>>(c1_W + 128 * 128, c1_wi, Wc + 1 * 128 * 384);
  gnn_prep_wc<<<128, 384, 0, stream>>>(c2_W,             c2_wi, Wc + 2 * 128 * 384);
  gnn_prep_wc<<<128, 384, 0, stream>>>(c2_W + 128 * 128, c2_wi, Wc + 3 * 128 * 384);
  gnn_prep_whT<<<256, 384, 0, stream>>>(c1_wh, c2_wh, whT);

  // ---- pack weights to MFMA B-frag bf16 ----
  for (int l = 0; l < 4; ++l) {
    const float* Wcl = Wc + (long)l * 128 * 384;
    const float* whl = whT + (long)(l >> 1) * 128 * 384;
    gnn_pack<<<16 * 8, 64, 0, stream>>>(Wcl, whl, 128, 384, 0,   8, pkRZ[l]);   // rz: K=256, N=256
    gnn_pack<<<8 * 4, 64, 0, stream>>>(Wcl, Wcl, 128, 384, 256, 4, pkAI[l]);    // ai: K=128, N=128
    gnn_pack<<<8 * 4, 64, 0, stream>>>(whl, whl, 128, 384, 256, 4, pkAH[l]);    // ah
  }
  gnn_pack<<<8 * 4, 64, 0, stream>>>(W_emb2, W_emb2, 128, 128, 0, 4, pe2);
  gnn_pack<<<8 * 4, 64, 0, stream>>>(W_g1,  W_g1,  128, 128, 0, 4, pg1);
  gnn_pack<<<8 * 4, 64, 0, stream>>>(W_g2,  W_g2,  128, 128, 0, 4, pg2);
  gnn_pack<<<16 * 4, 64, 0, stream>>>(W_l1, W_l1,  128, 256, 0, 4, pl1);        // x-part only (K=128,N=256)
  gnn_pack<<<8 * 8, 64, 0, stream>>>(W_l2,  W_l2,  256, 128, 0, 8, pl2);        // K=256,N=128

  // ---- embeddings: G -> xa -> xc ----
  gnn_gemm16<<<dim3(2, NODES / 64), 256, 0, stream>>>(G, W_emb1, b_emb1, xa, 128);
  gnn_mgemm<128, 128, 1, 0><<<NODES / 64, 256, 0, stream>>>(xa, pe2, b_emb2, xc);

  // ---- conv1 (x in xc) ----
  gnn_agg<<<NODES / 4, 256, 0, stream>>>(xc, rowptr, epack, tb);
  gnn_mgru<0><<<NODES / 64, 256, 0, stream>>>(tb, xc, pkRZ[0], pkAI[0], pkAH[0], c1_bi, c1_bh, xa);
  gnn_agg<<<NODES / 4, 256, 0, stream>>>(xa, rowptr, epack, tb);
  gnn_mgru<1><<<NODES / 64, 256, 0, stream>>>(tb, xa, pkRZ[1], pkAI[1], pkAH[1], c1_bi, c1_bh, xc);

  // ---- conv2 (x in xc) ----
  gnn_agg<<<NODES / 4, 256, 0, stream>>>(xc, rowptr, epack, tb);
  gnn_mgru<0><<<NODES / 64, 256, 0, stream>>>(tb, xc, pkRZ[2], pkAI[2], pkAH[2], c2_bi, c2_bh, xa);
  gnn_agg<<<NODES / 4, 256, 0, stream>>>(xa, rowptr, epack, tb);
  gnn_mgru<1><<<NODES / 64, 256, 0, stream>>>(tb, xa, pkRZ[3], pkAI[3], pkAH[3], c2_bi, c2_bh, xc);

  // ---- head GEMMs: xc -> xa -> tb (x3) ----
  gnn_mgemm<128, 128, 1, 0><<<NODES / 64, 256, 0, stream>>>(xc, pg1, b_g1, xa);
  gnn_mgemm<128, 128, 0, 0><<<NODES / 64, 256, 0, stream>>>(xa, pg2, b_g2, tb);

  // ---- pool + per-graph bias (folds ge @ W_l1[128:] + b_l1) ----
  gnn_pool<<<NB * 8, 128, 0, stream>>>(tb, ge);
  gnn_gbias<<<NB, 256, 0, stream>>>(ge, W_l1 + 128 * 256, b_l1, gb);

  // ---- MLP: l1 (graph-bias), l2, l3+reduction ----
  gnn_mgemm<128, 256, 1, 1><<<NODES / 64, 256, 0, stream>>>(tb, pl1, gb, u1b);
  gnn_mgemm<256, 128, 1, 0><<<NODES / 64, 256, 0, stream>>>(u1b, pl2, b_l2, xa);  // u2 in xa
  gnn_item<<<NB, 256, 0, stream>>>(iv, vvs, out);
  gnn_bound<<<NODES / 64, 256, 0, stream>>>(xa, W_l3, b_l3, vvs, out);
}